// Round 11
// baseline (782.928 us; speedup 1.0000x reference)
//
#include <hip/hip_runtime.h>

typedef unsigned short u16;
typedef __attribute__((ext_vector_type(8))) short bfrag;   // 8 x bf16
typedef __attribute__((ext_vector_type(4))) float ffrag;   // 4 x f32

#define LN_EPS 1e-5f

#define GLOAD16(g, l)                                                          \
    __builtin_amdgcn_global_load_lds(                                          \
        (const __attribute__((address_space(1))) void*)(g),                    \
        (__attribute__((address_space(3))) void*)(l), 16, 0, 0)

__device__ __forceinline__ u16 f2bf(float f) {
    unsigned u = __builtin_bit_cast(unsigned, f);
    u += 0x7fffu + ((u >> 16) & 1u);   // RNE
    return (u16)(u >> 16);
}

// windowed token index -> image row index
__device__ __forceinline__ int win_to_img(int tok) {
    int win = tok >> 9, n = tok & 511;
    int wh = win >> 4, ww = (win >> 2) & 3, wd = win & 3;
    int ph = n >> 6, pw = (n >> 3) & 7, pd = n & 7;
    return ((wh * 8 + ph) * 32 + (ww * 8 + pw)) * 32 + (wd * 8 + pd);
}

// LayerNorm over C=512, one wave per token.
__global__ __launch_bounds__(256) void k_ln(const float* __restrict__ x,
                                            const float* __restrict__ w,
                                            const float* __restrict__ b,
                                            u16* __restrict__ out, int windowed) {
    int wave = threadIdx.x >> 6, lane = threadIdx.x & 63;
    int tok = blockIdx.x * 4 + wave;
    int src = windowed ? win_to_img(tok) : tok;
    const float* xr = x + (size_t)src * 512;
    float v[8];
#pragma unroll
    for (int i = 0; i < 2; i++) {
        float4 f = *(const float4*)(xr + i * 256 + lane * 4);
        v[i * 4 + 0] = f.x; v[i * 4 + 1] = f.y; v[i * 4 + 2] = f.z; v[i * 4 + 3] = f.w;
    }
    float s = 0.f;
#pragma unroll
    for (int i = 0; i < 8; i++) s += v[i];
#pragma unroll
    for (int m = 1; m < 64; m <<= 1) s += __shfl_xor(s, m);
    float mean = s * (1.0f / 512.0f);
    float vs = 0.f;
#pragma unroll
    for (int i = 0; i < 8; i++) { float d = v[i] - mean; vs += d * d; }
#pragma unroll
    for (int m = 1; m < 64; m <<= 1) vs += __shfl_xor(vs, m);
    float rstd = rsqrtf(vs * (1.0f / 512.0f) + LN_EPS);
    u16* orow = out + (size_t)tok * 512;
#pragma unroll
    for (int i = 0; i < 2; i++) {
        int c0 = i * 256 + lane * 4;
        ushort4 o;
        o.x = f2bf((v[i * 4 + 0] - mean) * rstd * w[c0 + 0] + b[c0 + 0]);
        o.y = f2bf((v[i * 4 + 1] - mean) * rstd * w[c0 + 1] + b[c0 + 1]);
        o.z = f2bf((v[i * 4 + 2] - mean) * rstd * w[c0 + 2] + b[c0 + 2]);
        o.w = f2bf((v[i * 4 + 3] - mean) * rstd * w[c0 + 3] + b[c0 + 3]);
        *(ushort4*)(orow + c0) = o;
    }
}

// Merged prep: 4 weight transposes (f32 [K][N] -> bf16 [N][K]) + q scale/cast.
// All K are powers of two -> shifts. One launch replaces five.
__global__ __launch_bounds__(256) void k_prep(const float* __restrict__ kv_w,
                                              const float* __restrict__ proj_w,
                                              const float* __restrict__ fc1_w,
                                              const float* __restrict__ fc2_w,
                                              const float* __restrict__ q,
                                              u16* __restrict__ kv_wt,
                                              u16* __restrict__ proj_wt,
                                              u16* __restrict__ fc1_wt,
                                              u16* __restrict__ fc2_wt,
                                              u16* __restrict__ qbf) {
    int i = blockIdx.x * 256 + threadIdx.x;
    if (i < 524288) {                       // kv_wt [1024][512]
        int n = i >> 9, k = i & 511;
        kv_wt[i] = f2bf(kv_w[k * 1024 + n]);
    } else if (i < 786432) {                // proj_wt [512][512]
        int j = i - 524288, n = j >> 9, k = j & 511;
        proj_wt[j] = f2bf(proj_w[k * 512 + n]);
    } else if (i < 1835008) {               // fc1_wt [2048][512]
        int j = i - 786432, n = j >> 9, k = j & 511;
        fc1_wt[j] = f2bf(fc1_w[k * 2048 + n]);
    } else if (i < 2883584) {               // fc2_wt [512][2048]
        int j = i - 1835008, n = j >> 11, k = j & 2047;
        fc2_wt[j] = f2bf(fc2_w[k * 512 + n]);
    } else {                                // qbf [8*512*64], pre-scaled
        int j = i - 2883584;
        qbf[j] = f2bf(q[j] * 0.125f);
    }
}

// ==== 128x128 GEMM, BK=32, 4 waves (2x2), 2-phase dbuf (R7-proven best) ====
// C = A[M,K](bf16,K-contig) @ Bt[Nn,K](bf16,K-contig)^T + bias.
// Chunk-XOR swizzle both-sides: LDS[r][c] = global[r][c ^ f(r)], f(r)=(r^(r>>2))&3,
// via pre-swizzled global SOURCE (linear gload_lds dest); ds_read applies same XOR.
// 32KB LDS -> 5 blocks/CU (launch_bounds). grid: bn fastest + XCD chunking.
// Epilogues (bf16 outputs LDS-staged for 128B-coalesced stores):
// EPI 0: +bias -> K [win][h][key][d] (cols<512) / V^T [win][h][d][key] (cols>=512)
// EPI 1: +bias, scatter windowed->image, + resid(x) -> f32   (proj -> x1)
// EPI 2: +bias, exact GELU -> bf16                           (fc1 -> hid)
// EPI 3: +bias, + resid(x1) -> f32                           (fc2 -> out)
template <int EPI>
__global__ __launch_bounds__(256, 5) void k_gemm128(const u16* __restrict__ A,
                                                    const u16* __restrict__ Bt,
                                                    const float* __restrict__ bias,
                                                    void* __restrict__ Cout, int K, int Nn,
                                                    const float* __restrict__ resid,
                                                    void* __restrict__ Cout2) {
    __shared__ u16 As0[4096], Bs0[4096], As1[4096], Bs1[4096];
    int tid = threadIdx.x;
    int wave = tid >> 6, lane = tid & 63;
    int wr = wave >> 1, wc = wave & 1;

    int gx = Nn >> 7;
    int nwg = gridDim.x;
    int wg = blockIdx.x;
    int wgs = (wg & 7) * (nwg >> 3) + (wg >> 3);   // XCD chunking (nwg%8==0)
    int bn = wgs % gx, bm = wgs / gx;

    // staging: thread covers rows rt (and rt+16), chunk lane&3; pre-swizzled src.
    int rt = wave * 32 + (lane >> 2);
    int sxo = ((lane & 3) ^ ((rt ^ (rt >> 2)) & 3)) * 8;
    const u16* Ag = A + (size_t)(bm * 128 + rt) * K + sxo;
    const u16* Bg = Bt + (size_t)(bn * 128 + rt) * K + sxo;

    // fragment reads: row = base16 + fr -> phys chunk = g ^ ((fr^(fr>>2))&3)
    int fr = lane & 15, g = lane >> 4;
    int pco = (g ^ ((fr ^ (fr >> 2)) & 3)) * 8;

    ffrag acc[4][4] = {};

#define STAGE(AS, BS, k0)                                                      \
    {                                                                          \
        GLOAD16(Ag + (k0), AS + wave * 1024);                                  \
        GLOAD16(Ag + (k0) + 16 * K, AS + wave * 1024 + 512);                   \
        GLOAD16(Bg + (k0), BS + wave * 1024);                                  \
        GLOAD16(Bg + (k0) + 16 * K, BS + wave * 1024 + 512);                   \
    }
#define COMPUTE(AS, BS)                                                        \
    {                                                                          \
        bfrag a[4], b[4];                                                      \
        _Pragma("unroll") for (int m = 0; m < 4; m++)                          \
            a[m] = *(const bfrag*)(AS + (wr * 64 + m * 16 + fr) * 32 + pco);   \
        _Pragma("unroll") for (int n = 0; n < 4; n++)                          \
            b[n] = *(const bfrag*)(BS + (wc * 64 + n * 16 + fr) * 32 + pco);   \
        _Pragma("unroll") for (int m = 0; m < 4; m++)                          \
            _Pragma("unroll") for (int n = 0; n < 4; n++)                      \
                acc[m][n] = __builtin_amdgcn_mfma_f32_16x16x32_bf16(           \
                    a[m], b[n], acc[m][n], 0, 0, 0);                           \
    }

    int nt = K >> 5;   // even for all our K
    STAGE(As0, Bs0, 0);
    __syncthreads();
    int t = 0;
    for (; t + 2 < nt; t += 2) {
        STAGE(As1, Bs1, (t + 1) * 32);
        COMPUTE(As0, Bs0);
        __syncthreads();
        STAGE(As0, Bs0, (t + 2) * 32);
        COMPUTE(As1, Bs1);
        __syncthreads();
    }
    STAGE(As1, Bs1, (nt - 1) * 32);
    COMPUTE(As0, Bs0);
    __syncthreads();
    COMPUTE(As1, Bs1);
#undef STAGE
#undef COMPUTE

    int gcolb = bn * 128 + wc * 64;             // wave col base
    int grb = bm * 128 + wr * 64;               // wave row base

    if constexpr (EPI == 0 || EPI == 2) {
        __syncthreads();   // safe to reuse staging LDS
        u16* ep = (wave == 0) ? As0 : (wave == 1) ? Bs0 : (wave == 2) ? As1 : Bs1;
        int h = (gcolb >> 6) & 7;
        bool isK = (EPI == 2) || (gcolb < 512);
#pragma unroll
        for (int m = 0; m < 4; m++)
#pragma unroll
            for (int n = 0; n < 4; n++) {
                float bv = bias[gcolb + n * 16 + fr];
#pragma unroll
                for (int r = 0; r < 4; r++) {
                    int wq = m * 16 + g * 4 + r;     // row within quadrant
                    int wcc = n * 16 + fr;           // col within quadrant
                    float val = acc[m][n][r] + bv;
                    if constexpr (EPI == 2)
                        val = 0.5f * val * (1.0f + erff(val * 0.70710678118f));
                    if (isK)
                        ep[wq * 64 + (wcc ^ ((wq & 7) << 3))] = f2bf(val);
                    else   // V: transpose in LDS -> [d][key]
                        ep[wcc * 64 + (wq ^ ((wcc & 7) << 3))] = f2bf(val);
                }
            }
#pragma unroll
        for (int rd = 0; rd < 8; rd++) {
            int row = rd * 8 + (lane >> 3);
            int ch = (lane & 7) ^ (row & 7);
            int4 v = *(const int4*)(ep + row * 64 + ch * 8);
            if constexpr (EPI == 2) {
                int grow = grb + row;
                *(int4*)(&((u16*)Cout)[(size_t)grow * Nn + gcolb + (lane & 7) * 8]) = v;
            } else {
                if (isK) {
                    int tok = grb + row;
                    int win = tok >> 9, key = tok & 511;
                    *(int4*)(&((u16*)Cout)[(((size_t)(win * 8 + h)) * 512 + key) * 64 + (lane & 7) * 8]) = v;
                } else {
                    int win = grb >> 9, key0 = grb & 511;   // 64 keys same window
                    *(int4*)(&((u16*)Cout2)[(((size_t)(win * 8 + h)) * 64 + row) * 512 + key0 + (lane & 7) * 8]) = v;
                }
            }
        }
    } else {
#pragma unroll
        for (int m = 0; m < 4; m++)
#pragma unroll
            for (int n = 0; n < 4; n++) {
                int col = gcolb + n * 16 + fr;
                float bv = bias[col];
#pragma unroll
                for (int r = 0; r < 4; r++) {
                    int row = grb + m * 16 + g * 4 + r;
                    float val = acc[m][n][r] + bv;
                    if constexpr (EPI == 1) {
                        int ri = win_to_img(row);
                        size_t o = (size_t)ri * 512 + col;
                        ((float*)Cout)[o] = val + resid[o];
                    } else {
                        size_t o = (size_t)row * 512 + col;
                        ((float*)Cout)[o] = val + resid[o];
                    }
                }
            }
    }
}

// Flash attention: 4096 blocks (XCD-chunk swizzled), 4 waves x 16 q-rows.
// kb:  bf16 [win][h][key 512][d 64]  (PLAIN)
// vtb: bf16 [win][h][d 64][key 512]  (PLAIN)
// Staging: global_load_lds w=16 with pre-swizzled SOURCE chunks (linear LDS
// dest); LDS content [row][c] = true[row][c^(row&7)], reads XOR-deswizzle.
// Ps is [64][64] XOR-swizzled (col ^ ((row&7)<<3)) -> 40KB LDS, 4 blocks/CU.
__global__ __launch_bounds__(256, 4) void k_attn(const u16* __restrict__ qb,
                                                 const u16* __restrict__ kb,
                                                 const u16* __restrict__ vtb,
                                                 u16* __restrict__ o) {
    __shared__ u16 K0[4096], K1[4096], V0[4096], V1[4096];  // [row 64][64]
    __shared__ u16 Ps[4096];                                 // [64][64] swizzled
    int bid = blockIdx.x;
    int wg = (bid & 7) * 512 + (bid >> 3);   // bijective XCD chunking (4096%8==0)
    int qc = wg & 7;
    int pair = wg >> 3;
    int hh = pair & 7, win = pair >> 3;
    int wave = threadIdx.x >> 6, lane = threadIdx.x & 63;
    const u16* kbw = kb + ((size_t)(win * 8 + hh)) * 512 * 64;
    const u16* vtw = vtb + ((size_t)(win * 8 + hh)) * 64 * 512;

    const u16* qrow = qb + ((size_t)hh * 512 + qc * 64 + (wave << 4) + (lane & 15)) * 64 + (lane >> 4) * 8;
    bfrag aq0 = *(const bfrag*)(qrow);
    bfrag aq1 = *(const bfrag*)(qrow + 32);

    ffrag acc[4] = {};
    float m_run[4], l_run[4];
#pragma unroll
    for (int r = 0; r < 4; r++) { m_run[r] = -1e30f; l_run[r] = 0.0f; }

    int srow = lane >> 3;                        // sub-row within 8-row group
    int sxo = ((lane & 7) ^ srow) * 8;           // pre-swizzled source chunk
    int fr = lane & 15;
    int fkc = lane >> 4;                         // logical k-chunk 0..3
    int kx0 = (fkc ^ (fr & 7)) * 8;              // physical chunk, k 0..31
    int kx1 = ((fkc + 4) ^ (fr & 7)) * 8;        // k 32..63
    int arow = (wave << 4) + fr;
    int pswz = (arow & 7) << 3;                  // Ps read swizzle (arow&7 == fr&7)

#define STAGE_KV(KS, VS, kc)                                                   \
    {                                                                          \
        GLOAD16(kbw + (size_t)((kc) * 64 + wave * 8 + srow) * 64 + sxo,        \
                KS + wave * 512);                                              \
        GLOAD16(kbw + (size_t)((kc) * 64 + 32 + wave * 8 + srow) * 64 + sxo,   \
                KS + 2048 + wave * 512);                                       \
        GLOAD16(vtw + (size_t)(wave * 8 + srow) * 512 + (kc) * 64 + sxo,       \
                VS + wave * 512);                                              \
        GLOAD16(vtw + (size_t)(32 + wave * 8 + srow) * 512 + (kc) * 64 + sxo,  \
                VS + 2048 + wave * 512);                                       \
    }
#define ATT_COMPUTE(KS, VS)                                                    \
    {                                                                          \
        ffrag s[4] = {};                                                       \
        _Pragma("unroll") for (int j = 0; j < 4; j++) {                        \
            bfrag b0 = *(const bfrag*)(KS + (j * 16 + fr) * 64 + kx0);         \
            s[j] = __builtin_amdgcn_mfma_f32_16x16x32_bf16(aq0, b0, s[j], 0, 0, 0); \
            bfrag b1 = *(const bfrag*)(KS + (j * 16 + fr) * 64 + kx1);         \
            s[j] = __builtin_amdgcn_mfma_f32_16x16x32_bf16(aq1, b1, s[j], 0, 0, 0); \
        }                                                                      \
        _Pragma("unroll") for (int r = 0; r < 4; r++) {                        \
            float mx = fmaxf(fmaxf(s[0][r], s[1][r]), fmaxf(s[2][r], s[3][r]));\
            _Pragma("unroll") for (int d = 1; d < 16; d <<= 1)                 \
                mx = fmaxf(mx, __shfl_xor(mx, d));                             \
            float mnew = fmaxf(m_run[r], mx);                                  \
            float alpha = __expf(m_run[r] - mnew);                             \
            m_run[r] = mnew;                                                   \
            float rs = 0.0f;                                                   \
            _Pragma("unroll") for (int j = 0; j < 4; j++) {                    \
                float p = __expf(s[j][r] - mnew);                              \
                s[j][r] = p;                                                   \
                rs += p;                                                       \
            }                                                                  \
            _Pragma("unroll") for (int d = 1; d < 16; d <<= 1)                 \
                rs += __shfl_xor(rs, d);                                       \
            l_run[r] = l_run[r] * alpha + rs;                                  \
            _Pragma("unroll") for (int j = 0; j < 4; j++) acc[j][r] *= alpha;  \
        }                                                                      \
        _Pragma("unroll") for (int j = 0; j < 4; j++)                          \
            _Pragma("unroll") for (int r = 0; r < 4; r++) {                    \
                int prow = (wave << 4) + (lane >> 4) * 4 + r;                  \
                Ps[prow * 64 + ((j * 16 + fr) ^ ((prow & 7) << 3))] = f2bf(s[j][r]); \
            }                                                                  \
        bfrag ap0 = *(const bfrag*)(&Ps[arow * 64 + ((fkc * 8) ^ pswz)]);      \
        bfrag ap1 = *(const bfrag*)(&Ps[arow * 64 + ((32 + fkc * 8) ^ pswz)]); \
        _Pragma("unroll") for (int j = 0; j < 4; j++) {                        \
            bfrag v0 = *(const bfrag*)(VS + (j * 16 + fr) * 64 + kx0);         \
            acc[j] = __builtin_amdgcn_mfma_f32_16x16x32_bf16(ap0, v0, acc[j], 0, 0, 0); \
            bfrag v1 = *(const bfrag*)(VS + (j * 16 + fr) * 64 + kx1);         \
            acc[j] = __builtin_amdgcn_mfma_f32_16x16x32_bf16(ap1, v1, acc[j], 0, 0, 0); \
        }                                                                      \
    }

    STAGE_KV(K0, V0, 0);
    __syncthreads();
#pragma unroll 1
    for (int kc = 0; kc < 8; kc += 2) {
        if (kc + 1 < 8) STAGE_KV(K1, V1, kc + 1);
        ATT_COMPUTE(K0, V0);
        __syncthreads();
        if (kc + 2 < 8) STAGE_KV(K0, V0, kc + 2);
        ATT_COMPUTE(K1, V1);
        __syncthreads();
    }
#undef STAGE_KV
#undef ATT_COMPUTE

    int row0 = qc * 64 + (wave << 4) + (lane >> 4) * 4;
#pragma unroll
    for (int j = 0; j < 4; j++) {
        int col = hh * 64 + j * 16 + fr;
#pragma unroll
        for (int r = 0; r < 4; r++) {
            float val = acc[j][r] / l_run[r];
            o[((size_t)win * 512 + row0 + r) * 512 + col] = f2bf(val);
        }
    }
}

extern "C" void kernel_launch(void* const* d_in, const int* in_sizes, int n_in,
                              void* d_out, int out_size, void* d_ws, size_t ws_size,
                              hipStream_t stream) {
    const float* x      = (const float*)d_in[0];
    const float* q_ms   = (const float*)d_in[1];
    const float* n1w    = (const float*)d_in[2];
    const float* n1b    = (const float*)d_in[3];
    const float* kv_w   = (const float*)d_in[4];
    const float* kv_b   = (const float*)d_in[5];
    const float* proj_w = (const float*)d_in[6];
    const float* proj_b = (const float*)d_in[7];
    const float* n2w    = (const float*)d_in[8];
    const float* n2b    = (const float*)d_in[9];
    const float* fc1_w  = (const float*)d_in[10];
    const float* fc1_b  = (const float*)d_in[11];
    const float* fc2_w  = (const float*)d_in[12];
    const float* fc2_b  = (const float*)d_in[13];

    char* ws = (char*)d_ws;
    const size_t OFF_XNW = 0;           // bf16 [32768][512]   33,554,432 B
    const size_t OFF_KB  = 33554432;    // bf16 [64][8][512][64]  33,554,432 B
    const size_t OFF_VT  = 67108864;    // bf16 [64][8][64][512]  33,554,432 B
    const size_t OFF_O   = 100663296;   // bf16 [32768][512]   33,554,432 B
    const size_t OFF_HID = 0;           // bf16 [32768][2048] (aliases dead bufs)
    const size_t OFF_X1  = 134217728;   // f32  [32768][512]   67,108,864 B
    const size_t OFF_XN2 = 201326592;   // bf16 [32768][512]   33,554,432 B
    const size_t OFF_W   = 234881024;   // transposed weights + q
    u16* xnw = (u16*)(ws + OFF_XNW);
    u16* kbb = (u16*)(ws + OFF_KB);
    u16* vtb = (u16*)(ws + OFF_VT);
    u16* ob  = (u16*)(ws + OFF_O);
    u16* hid = (u16*)(ws + OFF_HID);
    float* x1 = (float*)(ws + OFF_X1);
    u16* xn2 = (u16*)(ws + OFF_XN2);
    u16* kv_wt   = (u16*)(ws + OFF_W);        // [1024][512]
    u16* proj_wt = kv_wt + 512 * 1024;        // [512][512]
    u16* fc1_wt  = proj_wt + 512 * 512;       // [2048][512]
    u16* fc2_wt  = fc1_wt + 512 * 2048;       // [512][2048]
    u16* qbf     = fc2_wt + 2048 * 512;       // [8][512][64]
    size_t need = OFF_W + (size_t)(512 * 1024 + 512 * 512 + 512 * 2048 + 2048 * 512 + 8 * 512 * 64) * 2;
    if (ws_size < need) return;

    k_ln<<<8192, 256, 0, stream>>>(x, n1w, n1b, xnw, 1);
    k_prep<<<12288, 256, 0, stream>>>(kv_w, proj_w, fc1_w, fc2_w, q_ms,
                                      kv_wt, proj_wt, fc1_wt, fc2_wt, qbf);

    k_gemm128<0><<<2048, 256, 0, stream>>>(xnw, kv_wt, kv_b, kbb, 512, 1024, nullptr, vtb);
    k_attn<<<dim3(4096), 256, 0, stream>>>(qbf, kbb, vtb, ob);
    k_gemm128<1><<<1024, 256, 0, stream>>>(ob, proj_wt, proj_b, x1, 512, 512, x, nullptr);
    k_ln<<<8192, 256, 0, stream>>>(x1, n2w, n2b, xn2, 0);
    k_gemm128<2><<<4096, 256, 0, stream>>>(xn2, fc1_wt, fc1_b, hid, 512, 2048, nullptr, nullptr);
    k_gemm128<3><<<1024, 256, 0, stream>>>(hid, fc2_wt, fc2_b, d_out, 2048, 512, x1, nullptr);
}

// Round 12
// 487.074 us; speedup vs baseline: 1.6074x; 1.6074x over previous
//
#include <hip/hip_runtime.h>

typedef unsigned short u16;
typedef __attribute__((ext_vector_type(8))) short bfrag;   // 8 x bf16
typedef __attribute__((ext_vector_type(4))) float ffrag;   // 4 x f32

#define LN_EPS 1e-5f

#define GLOAD16(g, l)                                                          \
    __builtin_amdgcn_global_load_lds(                                          \
        (const __attribute__((address_space(1))) void*)(g),                    \
        (__attribute__((address_space(3))) void*)(l), 16, 0, 0)

__device__ __forceinline__ u16 f2bf(float f) {
    unsigned u = __builtin_bit_cast(unsigned, f);
    u += 0x7fffu + ((u >> 16) & 1u);   // RNE
    return (u16)(u >> 16);
}

// windowed token index -> image row index
__device__ __forceinline__ int win_to_img(int tok) {
    int win = tok >> 9, n = tok & 511;
    int wh = win >> 4, ww = (win >> 2) & 3, wd = win & 3;
    int ph = n >> 6, pw = (n >> 3) & 7, pd = n & 7;
    return ((wh * 8 + ph) * 32 + (ww * 8 + pw)) * 32 + (wd * 8 + pd);
}

// LayerNorm over C=512, one wave per token.
__global__ __launch_bounds__(256) void k_ln(const float* __restrict__ x,
                                            const float* __restrict__ w,
                                            const float* __restrict__ b,
                                            u16* __restrict__ out, int windowed) {
    int wave = threadIdx.x >> 6, lane = threadIdx.x & 63;
    int tok = blockIdx.x * 4 + wave;
    int src = windowed ? win_to_img(tok) : tok;
    const float* xr = x + (size_t)src * 512;
    float v[8];
#pragma unroll
    for (int i = 0; i < 2; i++) {
        float4 f = *(const float4*)(xr + i * 256 + lane * 4);
        v[i * 4 + 0] = f.x; v[i * 4 + 1] = f.y; v[i * 4 + 2] = f.z; v[i * 4 + 3] = f.w;
    }
    float s = 0.f;
#pragma unroll
    for (int i = 0; i < 8; i++) s += v[i];
#pragma unroll
    for (int m = 1; m < 64; m <<= 1) s += __shfl_xor(s, m);
    float mean = s * (1.0f / 512.0f);
    float vs = 0.f;
#pragma unroll
    for (int i = 0; i < 8; i++) { float d = v[i] - mean; vs += d * d; }
#pragma unroll
    for (int m = 1; m < 64; m <<= 1) vs += __shfl_xor(vs, m);
    float rstd = rsqrtf(vs * (1.0f / 512.0f) + LN_EPS);
    u16* orow = out + (size_t)tok * 512;
#pragma unroll
    for (int i = 0; i < 2; i++) {
        int c0 = i * 256 + lane * 4;
        ushort4 o;
        o.x = f2bf((v[i * 4 + 0] - mean) * rstd * w[c0 + 0] + b[c0 + 0]);
        o.y = f2bf((v[i * 4 + 1] - mean) * rstd * w[c0 + 1] + b[c0 + 1]);
        o.z = f2bf((v[i * 4 + 2] - mean) * rstd * w[c0 + 2] + b[c0 + 2]);
        o.w = f2bf((v[i * 4 + 3] - mean) * rstd * w[c0 + 3] + b[c0 + 3]);
        *(ushort4*)(orow + c0) = o;
    }
}

// Merged prep: 4 weight transposes (f32 [K][N] -> bf16 [N][K]) + q scale/cast.
// All K are powers of two -> shifts. One launch replaces five.
__global__ __launch_bounds__(256) void k_prep(const float* __restrict__ kv_w,
                                              const float* __restrict__ proj_w,
                                              const float* __restrict__ fc1_w,
                                              const float* __restrict__ fc2_w,
                                              const float* __restrict__ q,
                                              u16* __restrict__ kv_wt,
                                              u16* __restrict__ proj_wt,
                                              u16* __restrict__ fc1_wt,
                                              u16* __restrict__ fc2_wt,
                                              u16* __restrict__ qbf) {
    int i = blockIdx.x * 256 + threadIdx.x;
    if (i < 524288) {                       // kv_wt [1024][512]
        int n = i >> 9, k = i & 511;
        kv_wt[i] = f2bf(kv_w[k * 1024 + n]);
    } else if (i < 786432) {                // proj_wt [512][512]
        int j = i - 524288, n = j >> 9, k = j & 511;
        proj_wt[j] = f2bf(proj_w[k * 512 + n]);
    } else if (i < 1835008) {               // fc1_wt [2048][512]
        int j = i - 786432, n = j >> 9, k = j & 511;
        fc1_wt[j] = f2bf(fc1_w[k * 2048 + n]);
    } else if (i < 2883584) {               // fc2_wt [512][2048]
        int j = i - 1835008, n = j >> 11, k = j & 2047;
        fc2_wt[j] = f2bf(fc2_w[k * 512 + n]);
    } else {                                // qbf [8*512*64], pre-scaled
        int j = i - 2883584;
        qbf[j] = f2bf(q[j] * 0.125f);
    }
}

// ==== 128x128 GEMM, BK=32, 4 waves (2x2), 2-phase dbuf (R7-proven best) ====
// C = A[M,K](bf16,K-contig) @ Bt[Nn,K](bf16,K-contig)^T + bias.
// Chunk-XOR swizzle both-sides: LDS[r][c] = global[r][c ^ f(r)], f(r)=(r^(r>>2))&3,
// via pre-swizzled global SOURCE (linear gload_lds dest); ds_read applies same XOR.
// launch_bounds(256,4): 64 VGPR + 64 AGPR fits 4 waves/EU (512-reg pool);
// (256,5) forced VGPR->48 and spilled (R11: WRITE_SIZE 131->599MB, 2x slower).
// Epilogues (bf16 outputs LDS-staged for 128B-coalesced stores):
// EPI 0: +bias -> K [win][h][key][d] (cols<512) / V^T [win][h][d][key] (cols>=512)
// EPI 1: +bias, scatter windowed->image, + resid(x) -> f32   (proj -> x1)
// EPI 2: +bias, exact GELU -> bf16                           (fc1 -> hid)
// EPI 3: +bias, + resid(x1) -> f32                           (fc2 -> out)
template <int EPI>
__global__ __launch_bounds__(256, 4) void k_gemm128(const u16* __restrict__ A,
                                                    const u16* __restrict__ Bt,
                                                    const float* __restrict__ bias,
                                                    void* __restrict__ Cout, int K, int Nn,
                                                    const float* __restrict__ resid,
                                                    void* __restrict__ Cout2) {
    __shared__ u16 As0[4096], Bs0[4096], As1[4096], Bs1[4096];
    int tid = threadIdx.x;
    int wave = tid >> 6, lane = tid & 63;
    int wr = wave >> 1, wc = wave & 1;

    int gx = Nn >> 7;
    int nwg = gridDim.x;
    int wg = blockIdx.x;
    int wgs = (wg & 7) * (nwg >> 3) + (wg >> 3);   // XCD chunking (nwg%8==0)
    int bn = wgs % gx, bm = wgs / gx;

    // staging: thread covers rows rt (and rt+16), chunk lane&3; pre-swizzled src.
    int rt = wave * 32 + (lane >> 2);
    int sxo = ((lane & 3) ^ ((rt ^ (rt >> 2)) & 3)) * 8;
    const u16* Ag = A + (size_t)(bm * 128 + rt) * K + sxo;
    const u16* Bg = Bt + (size_t)(bn * 128 + rt) * K + sxo;

    // fragment reads: row = base16 + fr -> phys chunk = g ^ ((fr^(fr>>2))&3)
    int fr = lane & 15, g = lane >> 4;
    int pco = (g ^ ((fr ^ (fr >> 2)) & 3)) * 8;

    ffrag acc[4][4] = {};

#define STAGE(AS, BS, k0)                                                      \
    {                                                                          \
        GLOAD16(Ag + (k0), AS + wave * 1024);                                  \
        GLOAD16(Ag + (k0) + 16 * K, AS + wave * 1024 + 512);                   \
        GLOAD16(Bg + (k0), BS + wave * 1024);                                  \
        GLOAD16(Bg + (k0) + 16 * K, BS + wave * 1024 + 512);                   \
    }
#define COMPUTE(AS, BS)                                                        \
    {                                                                          \
        bfrag a[4], b[4];                                                      \
        _Pragma("unroll") for (int m = 0; m < 4; m++)                          \
            a[m] = *(const bfrag*)(AS + (wr * 64 + m * 16 + fr) * 32 + pco);   \
        _Pragma("unroll") for (int n = 0; n < 4; n++)                          \
            b[n] = *(const bfrag*)(BS + (wc * 64 + n * 16 + fr) * 32 + pco);   \
        _Pragma("unroll") for (int m = 0; m < 4; m++)                          \
            _Pragma("unroll") for (int n = 0; n < 4; n++)                      \
                acc[m][n] = __builtin_amdgcn_mfma_f32_16x16x32_bf16(           \
                    a[m], b[n], acc[m][n], 0, 0, 0);                           \
    }

    int nt = K >> 5;   // even for all our K
    STAGE(As0, Bs0, 0);
    __syncthreads();
    int t = 0;
    for (; t + 2 < nt; t += 2) {
        STAGE(As1, Bs1, (t + 1) * 32);
        COMPUTE(As0, Bs0);
        __syncthreads();
        STAGE(As0, Bs0, (t + 2) * 32);
        COMPUTE(As1, Bs1);
        __syncthreads();
    }
    STAGE(As1, Bs1, (nt - 1) * 32);
    COMPUTE(As0, Bs0);
    __syncthreads();
    COMPUTE(As1, Bs1);
#undef STAGE
#undef COMPUTE

    int gcolb = bn * 128 + wc * 64;             // wave col base
    int grb = bm * 128 + wr * 64;               // wave row base

    if constexpr (EPI == 0 || EPI == 2) {
        __syncthreads();   // safe to reuse staging LDS
        u16* ep = (wave == 0) ? As0 : (wave == 1) ? Bs0 : (wave == 2) ? As1 : Bs1;
        int h = (gcolb >> 6) & 7;
        bool isK = (EPI == 2) || (gcolb < 512);
#pragma unroll
        for (int m = 0; m < 4; m++)
#pragma unroll
            for (int n = 0; n < 4; n++) {
                float bv = bias[gcolb + n * 16 + fr];
#pragma unroll
                for (int r = 0; r < 4; r++) {
                    int wq = m * 16 + g * 4 + r;     // row within quadrant
                    int wcc = n * 16 + fr;           // col within quadrant
                    float val = acc[m][n][r] + bv;
                    if constexpr (EPI == 2)
                        val = 0.5f * val * (1.0f + erff(val * 0.70710678118f));
                    if (isK)
                        ep[wq * 64 + (wcc ^ ((wq & 7) << 3))] = f2bf(val);
                    else   // V: transpose in LDS -> [d][key]
                        ep[wcc * 64 + (wq ^ ((wcc & 7) << 3))] = f2bf(val);
                }
            }
#pragma unroll
        for (int rd = 0; rd < 8; rd++) {
            int row = rd * 8 + (lane >> 3);
            int ch = (lane & 7) ^ (row & 7);
            int4 v = *(const int4*)(ep + row * 64 + ch * 8);
            if constexpr (EPI == 2) {
                int grow = grb + row;
                *(int4*)(&((u16*)Cout)[(size_t)grow * Nn + gcolb + (lane & 7) * 8]) = v;
            } else {
                if (isK) {
                    int tok = grb + row;
                    int win = tok >> 9, key = tok & 511;
                    *(int4*)(&((u16*)Cout)[(((size_t)(win * 8 + h)) * 512 + key) * 64 + (lane & 7) * 8]) = v;
                } else {
                    int win = grb >> 9, key0 = grb & 511;   // 64 keys same window
                    *(int4*)(&((u16*)Cout2)[(((size_t)(win * 8 + h)) * 64 + row) * 512 + key0 + (lane & 7) * 8]) = v;
                }
            }
        }
    } else {
#pragma unroll
        for (int m = 0; m < 4; m++)
#pragma unroll
            for (int n = 0; n < 4; n++) {
                int col = gcolb + n * 16 + fr;
                float bv = bias[col];
#pragma unroll
                for (int r = 0; r < 4; r++) {
                    int row = grb + m * 16 + g * 4 + r;
                    float val = acc[m][n][r] + bv;
                    if constexpr (EPI == 1) {
                        int ri = win_to_img(row);
                        size_t o = (size_t)ri * 512 + col;
                        ((float*)Cout)[o] = val + resid[o];
                    } else {
                        size_t o = (size_t)row * 512 + col;
                        ((float*)Cout)[o] = val + resid[o];
                    }
                }
            }
    }
}

// Flash attention: 4096 blocks (XCD-chunk swizzled), 4 waves x 16 q-rows.
// kb:  bf16 [win][h][key 512][d 64]  (PLAIN)
// vtb: bf16 [win][h][d 64][key 512]  (PLAIN)
// Staging: global_load_lds w=16 with pre-swizzled SOURCE chunks (linear LDS
// dest); LDS content [row][c] = true[row][c^(row&7)], reads XOR-deswizzle.
// Ps is [64][64] XOR-swizzled (col ^ ((row&7)<<3)) -> 40KB LDS, 4 blocks/CU.
__global__ __launch_bounds__(256, 4) void k_attn(const u16* __restrict__ qb,
                                                 const u16* __restrict__ kb,
                                                 const u16* __restrict__ vtb,
                                                 u16* __restrict__ o) {
    __shared__ u16 K0[4096], K1[4096], V0[4096], V1[4096];  // [row 64][64]
    __shared__ u16 Ps[4096];                                 // [64][64] swizzled
    int bid = blockIdx.x;
    int wg = (bid & 7) * 512 + (bid >> 3);   // bijective XCD chunking (4096%8==0)
    int qc = wg & 7;
    int pair = wg >> 3;
    int hh = pair & 7, win = pair >> 3;
    int wave = threadIdx.x >> 6, lane = threadIdx.x & 63;
    const u16* kbw = kb + ((size_t)(win * 8 + hh)) * 512 * 64;
    const u16* vtw = vtb + ((size_t)(win * 8 + hh)) * 64 * 512;

    const u16* qrow = qb + ((size_t)hh * 512 + qc * 64 + (wave << 4) + (lane & 15)) * 64 + (lane >> 4) * 8;
    bfrag aq0 = *(const bfrag*)(qrow);
    bfrag aq1 = *(const bfrag*)(qrow + 32);

    ffrag acc[4] = {};
    float m_run[4], l_run[4];
#pragma unroll
    for (int r = 0; r < 4; r++) { m_run[r] = -1e30f; l_run[r] = 0.0f; }

    int srow = lane >> 3;                        // sub-row within 8-row group
    int sxo = ((lane & 7) ^ srow) * 8;           // pre-swizzled source chunk
    int fr = lane & 15;
    int fkc = lane >> 4;                         // logical k-chunk 0..3
    int kx0 = (fkc ^ (fr & 7)) * 8;              // physical chunk, k 0..31
    int kx1 = ((fkc + 4) ^ (fr & 7)) * 8;        // k 32..63
    int arow = (wave << 4) + fr;
    int pswz = (arow & 7) << 3;                  // Ps read swizzle (arow&7 == fr&7)

#define STAGE_KV(KS, VS, kc)                                                   \
    {                                                                          \
        GLOAD16(kbw + (size_t)((kc) * 64 + wave * 8 + srow) * 64 + sxo,        \
                KS + wave * 512);                                              \
        GLOAD16(kbw + (size_t)((kc) * 64 + 32 + wave * 8 + srow) * 64 + sxo,   \
                KS + 2048 + wave * 512);                                       \
        GLOAD16(vtw + (size_t)(wave * 8 + srow) * 512 + (kc) * 64 + sxo,       \
                VS + wave * 512);                                              \
        GLOAD16(vtw + (size_t)(32 + wave * 8 + srow) * 512 + (kc) * 64 + sxo,  \
                VS + 2048 + wave * 512);                                       \
    }
#define ATT_COMPUTE(KS, VS)                                                    \
    {                                                                          \
        ffrag s[4] = {};                                                       \
        _Pragma("unroll") for (int j = 0; j < 4; j++) {                        \
            bfrag b0 = *(const bfrag*)(KS + (j * 16 + fr) * 64 + kx0);         \
            s[j] = __builtin_amdgcn_mfma_f32_16x16x32_bf16(aq0, b0, s[j], 0, 0, 0); \
            bfrag b1 = *(const bfrag*)(KS + (j * 16 + fr) * 64 + kx1);         \
            s[j] = __builtin_amdgcn_mfma_f32_16x16x32_bf16(aq1, b1, s[j], 0, 0, 0); \
        }                                                                      \
        _Pragma("unroll") for (int r = 0; r < 4; r++) {                        \
            float mx = fmaxf(fmaxf(s[0][r], s[1][r]), fmaxf(s[2][r], s[3][r]));\
            _Pragma("unroll") for (int d = 1; d < 16; d <<= 1)                 \
                mx = fmaxf(mx, __shfl_xor(mx, d));                             \
            float mnew = fmaxf(m_run[r], mx);                                  \
            float alpha = __expf(m_run[r] - mnew);                             \
            m_run[r] = mnew;                                                   \
            float rs = 0.0f;                                                   \
            _Pragma("unroll") for (int j = 0; j < 4; j++) {                    \
                float p = __expf(s[j][r] - mnew);                              \
                s[j][r] = p;                                                   \
                rs += p;                                                       \
            }                                                                  \
            _Pragma("unroll") for (int d = 1; d < 16; d <<= 1)                 \
                rs += __shfl_xor(rs, d);                                       \
            l_run[r] = l_run[r] * alpha + rs;                                  \
            _Pragma("unroll") for (int j = 0; j < 4; j++) acc[j][r] *= alpha;  \
        }                                                                      \
        _Pragma("unroll") for (int j = 0; j < 4; j++)                          \
            _Pragma("unroll") for (int r = 0; r < 4; r++) {                    \
                int prow = (wave << 4) + (lane >> 4) * 4 + r;                  \
                Ps[prow * 64 + ((j * 16 + fr) ^ ((prow & 7) << 3))] = f2bf(s[j][r]); \
            }                                                                  \
        bfrag ap0 = *(const bfrag*)(&Ps[arow * 64 + ((fkc * 8) ^ pswz)]);      \
        bfrag ap1 = *(const bfrag*)(&Ps[arow * 64 + ((32 + fkc * 8) ^ pswz)]); \
        _Pragma("unroll") for (int j = 0; j < 4; j++) {                        \
            bfrag v0 = *(const bfrag*)(VS + (j * 16 + fr) * 64 + kx0);         \
            acc[j] = __builtin_amdgcn_mfma_f32_16x16x32_bf16(ap0, v0, acc[j], 0, 0, 0); \
            bfrag v1 = *(const bfrag*)(VS + (j * 16 + fr) * 64 + kx1);         \
            acc[j] = __builtin_amdgcn_mfma_f32_16x16x32_bf16(ap1, v1, acc[j], 0, 0, 0); \
        }                                                                      \
    }

    STAGE_KV(K0, V0, 0);
    __syncthreads();
#pragma unroll 1
    for (int kc = 0; kc < 8; kc += 2) {
        if (kc + 1 < 8) STAGE_KV(K1, V1, kc + 1);
        ATT_COMPUTE(K0, V0);
        __syncthreads();
        if (kc + 2 < 8) STAGE_KV(K0, V0, kc + 2);
        ATT_COMPUTE(K1, V1);
        __syncthreads();
    }
#undef STAGE_KV
#undef ATT_COMPUTE

    int row0 = qc * 64 + (wave << 4) + (lane >> 4) * 4;
#pragma unroll
    for (int j = 0; j < 4; j++) {
        int col = hh * 64 + j * 16 + fr;
#pragma unroll
        for (int r = 0; r < 4; r++) {
            float val = acc[j][r] / l_run[r];
            o[((size_t)win * 512 + row0 + r) * 512 + col] = f2bf(val);
        }
    }
}

extern "C" void kernel_launch(void* const* d_in, const int* in_sizes, int n_in,
                              void* d_out, int out_size, void* d_ws, size_t ws_size,
                              hipStream_t stream) {
    const float* x      = (const float*)d_in[0];
    const float* q_ms   = (const float*)d_in[1];
    const float* n1w    = (const float*)d_in[2];
    const float* n1b    = (const float*)d_in[3];
    const float* kv_w   = (const float*)d_in[4];
    const float* kv_b   = (const float*)d_in[5];
    const float* proj_w = (const float*)d_in[6];
    const float* proj_b = (const float*)d_in[7];
    const float* n2w    = (const float*)d_in[8];
    const float* n2b    = (const float*)d_in[9];
    const float* fc1_w  = (const float*)d_in[10];
    const float* fc1_b  = (const float*)d_in[11];
    const float* fc2_w  = (const float*)d_in[12];
    const float* fc2_b  = (const float*)d_in[13];

    char* ws = (char*)d_ws;
    const size_t OFF_XNW = 0;           // bf16 [32768][512]   33,554,432 B
    const size_t OFF_KB  = 33554432;    // bf16 [64][8][512][64]  33,554,432 B
    const size_t OFF_VT  = 67108864;    // bf16 [64][8][64][512]  33,554,432 B
    const size_t OFF_O   = 100663296;   // bf16 [32768][512]   33,554,432 B
    const size_t OFF_HID = 0;           // bf16 [32768][2048] (aliases dead bufs)
    const size_t OFF_X1  = 134217728;   // f32  [32768][512]   67,108,864 B
    const size_t OFF_XN2 = 201326592;   // bf16 [32768][512]   33,554,432 B
    const size_t OFF_W   = 234881024;   // transposed weights + q
    u16* xnw = (u16*)(ws + OFF_XNW);
    u16* kbb = (u16*)(ws + OFF_KB);
    u16* vtb = (u16*)(ws + OFF_VT);
    u16* ob  = (u16*)(ws + OFF_O);
    u16* hid = (u16*)(ws + OFF_HID);
    float* x1 = (float*)(ws + OFF_X1);
    u16* xn2 = (u16*)(ws + OFF_XN2);
    u16* kv_wt   = (u16*)(ws + OFF_W);        // [1024][512]
    u16* proj_wt = kv_wt + 512 * 1024;        // [512][512]
    u16* fc1_wt  = proj_wt + 512 * 512;       // [2048][512]
    u16* fc2_wt  = fc1_wt + 512 * 2048;       // [512][2048]
    u16* qbf     = fc2_wt + 2048 * 512;       // [8][512][64]
    size_t need = OFF_W + (size_t)(512 * 1024 + 512 * 512 + 512 * 2048 + 2048 * 512 + 8 * 512 * 64) * 2;
    if (ws_size < need) return;

    k_ln<<<8192, 256, 0, stream>>>(x, n1w, n1b, xnw, 1);
    k_prep<<<12288, 256, 0, stream>>>(kv_w, proj_w, fc1_w, fc2_w, q_ms,
                                      kv_wt, proj_wt, fc1_wt, fc2_wt, qbf);

    k_gemm128<0><<<2048, 256, 0, stream>>>(xnw, kv_wt, kv_b, kbb, 512, 1024, nullptr, vtb);
    k_attn<<<dim3(4096), 256, 0, stream>>>(qbf, kbb, vtb, ob);
    k_gemm128<1><<<1024, 256, 0, stream>>>(ob, proj_wt, proj_b, x1, 512, 512, x, nullptr);
    k_ln<<<8192, 256, 0, stream>>>(x1, n2w, n2b, xn2, 0);
    k_gemm128<2><<<4096, 256, 0, stream>>>(xn2, fc1_wt, fc1_b, hid, 512, 2048, nullptr, nullptr);
    k_gemm128<3><<<1024, 256, 0, stream>>>(hid, fc2_wt, fc2_b, d_out, 2048, 512, x1, nullptr);
}

// Round 13
// 450.401 us; speedup vs baseline: 1.7383x; 1.0814x over previous
//
#include <hip/hip_runtime.h>

typedef unsigned short u16;
typedef __attribute__((ext_vector_type(8))) short bfrag;   // 8 x bf16
typedef __attribute__((ext_vector_type(4))) float ffrag;   // 4 x f32

#define LN_EPS 1e-5f

#define GLOAD16(g, l)                                                          \
    __builtin_amdgcn_global_load_lds(                                          \
        (const __attribute__((address_space(1))) void*)(g),                    \
        (__attribute__((address_space(3))) void*)(l), 16, 0, 0)

__device__ __forceinline__ u16 f2bf(float f) {
    unsigned u = __builtin_bit_cast(unsigned, f);
    u += 0x7fffu + ((u >> 16) & 1u);   // RNE
    return (u16)(u >> 16);
}

// windowed token index -> image row index
__device__ __forceinline__ int win_to_img(int tok) {
    int win = tok >> 9, n = tok & 511;
    int wh = win >> 4, ww = (win >> 2) & 3, wd = win & 3;
    int ph = n >> 6, pw = (n >> 3) & 7, pd = n & 7;
    return ((wh * 8 + ph) * 32 + (ww * 8 + pw)) * 32 + (wd * 8 + pd);
}

// LayerNorm over C=512, one wave per token.
__global__ __launch_bounds__(256) void k_ln(const float* __restrict__ x,
                                            const float* __restrict__ w,
                                            const float* __restrict__ b,
                                            u16* __restrict__ out, int windowed) {
    int wave = threadIdx.x >> 6, lane = threadIdx.x & 63;
    int tok = blockIdx.x * 4 + wave;
    int src = windowed ? win_to_img(tok) : tok;
    const float* xr = x + (size_t)src * 512;
    float v[8];
#pragma unroll
    for (int i = 0; i < 2; i++) {
        float4 f = *(const float4*)(xr + i * 256 + lane * 4);
        v[i * 4 + 0] = f.x; v[i * 4 + 1] = f.y; v[i * 4 + 2] = f.z; v[i * 4 + 3] = f.w;
    }
    float s = 0.f;
#pragma unroll
    for (int i = 0; i < 8; i++) s += v[i];
#pragma unroll
    for (int m = 1; m < 64; m <<= 1) s += __shfl_xor(s, m);
    float mean = s * (1.0f / 512.0f);
    float vs = 0.f;
#pragma unroll
    for (int i = 0; i < 8; i++) { float d = v[i] - mean; vs += d * d; }
#pragma unroll
    for (int m = 1; m < 64; m <<= 1) vs += __shfl_xor(vs, m);
    float rstd = rsqrtf(vs * (1.0f / 512.0f) + LN_EPS);
    u16* orow = out + (size_t)tok * 512;
#pragma unroll
    for (int i = 0; i < 2; i++) {
        int c0 = i * 256 + lane * 4;
        ushort4 o;
        o.x = f2bf((v[i * 4 + 0] - mean) * rstd * w[c0 + 0] + b[c0 + 0]);
        o.y = f2bf((v[i * 4 + 1] - mean) * rstd * w[c0 + 1] + b[c0 + 1]);
        o.z = f2bf((v[i * 4 + 2] - mean) * rstd * w[c0 + 2] + b[c0 + 2]);
        o.w = f2bf((v[i * 4 + 3] - mean) * rstd * w[c0 + 3] + b[c0 + 3]);
        *(ushort4*)(orow + c0) = o;
    }
}

// Merged prep: 4 weight transposes (f32 [K][N] -> bf16 [N][K]) + q scale/cast.
__global__ __launch_bounds__(256) void k_prep(const float* __restrict__ kv_w,
                                              const float* __restrict__ proj_w,
                                              const float* __restrict__ fc1_w,
                                              const float* __restrict__ fc2_w,
                                              const float* __restrict__ q,
                                              u16* __restrict__ kv_wt,
                                              u16* __restrict__ proj_wt,
                                              u16* __restrict__ fc1_wt,
                                              u16* __restrict__ fc2_wt,
                                              u16* __restrict__ qbf) {
    int i = blockIdx.x * 256 + threadIdx.x;
    if (i < 524288) {                       // kv_wt [1024][512]
        int n = i >> 9, k = i & 511;
        kv_wt[i] = f2bf(kv_w[k * 1024 + n]);
    } else if (i < 786432) {                // proj_wt [512][512]
        int j = i - 524288, n = j >> 9, k = j & 511;
        proj_wt[j] = f2bf(proj_w[k * 512 + n]);
    } else if (i < 1835008) {               // fc1_wt [2048][512]
        int j = i - 786432, n = j >> 9, k = j & 511;
        fc1_wt[j] = f2bf(fc1_w[k * 2048 + n]);
    } else if (i < 2883584) {               // fc2_wt [512][2048]
        int j = i - 1835008, n = j >> 11, k = j & 2047;
        fc2_wt[j] = f2bf(fc2_w[k * 512 + n]);
    } else {                                // qbf [8*512*64], pre-scaled
        int j = i - 2883584;
        qbf[j] = f2bf(q[j] * 0.125f);
    }
}

// ==== 128x128 GEMM, BK=32, 4 waves (2x2), 2-phase dbuf (R7-proven best) ====
// launch_bounds(256,4): 64 VGPR + 64 AGPR; (256,5) spilled (R11 post-mortem).
// EPI 2 GELU: tanh-form via sigmoid identity 0.5x(1+tanh(y)) = x*sigma(2y)
// (~7 VALU vs erff ~20+; max err ~3e-4). R12 PMC: fc1 VALUBusy 77% was
// erff-epilogue-bound.
// EPI 0: +bias -> K [win][h][key][d] (cols<512) / V^T [win][h][d][key] (cols>=512)
// EPI 1: +bias, scatter windowed->image, + resid(x) -> f32   (proj -> x1)
// EPI 2: +bias, tanh-GELU -> bf16                            (fc1 -> hid)
// EPI 3: +bias, + resid(x1) -> f32                           (fc2 -> out)
template <int EPI>
__global__ __launch_bounds__(256, 4) void k_gemm128(const u16* __restrict__ A,
                                                    const u16* __restrict__ Bt,
                                                    const float* __restrict__ bias,
                                                    void* __restrict__ Cout, int K, int Nn,
                                                    const float* __restrict__ resid,
                                                    void* __restrict__ Cout2) {
    __shared__ u16 As0[4096], Bs0[4096], As1[4096], Bs1[4096];
    int tid = threadIdx.x;
    int wave = tid >> 6, lane = tid & 63;
    int wr = wave >> 1, wc = wave & 1;

    int gx = Nn >> 7;
    int nwg = gridDim.x;
    int wg = blockIdx.x;
    int wgs = (wg & 7) * (nwg >> 3) + (wg >> 3);   // XCD chunking (nwg%8==0)
    int bn = wgs % gx, bm = wgs / gx;

    // staging: thread covers rows rt (and rt+16), chunk lane&3; pre-swizzled src.
    int rt = wave * 32 + (lane >> 2);
    int sxo = ((lane & 3) ^ ((rt ^ (rt >> 2)) & 3)) * 8;
    const u16* Ag = A + (size_t)(bm * 128 + rt) * K + sxo;
    const u16* Bg = Bt + (size_t)(bn * 128 + rt) * K + sxo;

    // fragment reads: row = base16 + fr -> phys chunk = g ^ ((fr^(fr>>2))&3)
    int fr = lane & 15, g = lane >> 4;
    int pco = (g ^ ((fr ^ (fr >> 2)) & 3)) * 8;

    ffrag acc[4][4] = {};

#define STAGE(AS, BS, k0)                                                      \
    {                                                                          \
        GLOAD16(Ag + (k0), AS + wave * 1024);                                  \
        GLOAD16(Ag + (k0) + 16 * K, AS + wave * 1024 + 512);                   \
        GLOAD16(Bg + (k0), BS + wave * 1024);                                  \
        GLOAD16(Bg + (k0) + 16 * K, BS + wave * 1024 + 512);                   \
    }
#define COMPUTE(AS, BS)                                                        \
    {                                                                          \
        bfrag a[4], b[4];                                                      \
        _Pragma("unroll") for (int m = 0; m < 4; m++)                          \
            a[m] = *(const bfrag*)(AS + (wr * 64 + m * 16 + fr) * 32 + pco);   \
        _Pragma("unroll") for (int n = 0; n < 4; n++)                          \
            b[n] = *(const bfrag*)(BS + (wc * 64 + n * 16 + fr) * 32 + pco);   \
        _Pragma("unroll") for (int m = 0; m < 4; m++)                          \
            _Pragma("unroll") for (int n = 0; n < 4; n++)                      \
                acc[m][n] = __builtin_amdgcn_mfma_f32_16x16x32_bf16(           \
                    a[m], b[n], acc[m][n], 0, 0, 0);                           \
    }

    int nt = K >> 5;   // even for all our K
    STAGE(As0, Bs0, 0);
    __syncthreads();
    int t = 0;
    for (; t + 2 < nt; t += 2) {
        STAGE(As1, Bs1, (t + 1) * 32);
        COMPUTE(As0, Bs0);
        __syncthreads();
        STAGE(As0, Bs0, (t + 2) * 32);
        COMPUTE(As1, Bs1);
        __syncthreads();
    }
    STAGE(As1, Bs1, (nt - 1) * 32);
    COMPUTE(As0, Bs0);
    __syncthreads();
    COMPUTE(As1, Bs1);
#undef STAGE
#undef COMPUTE

    int gcolb = bn * 128 + wc * 64;             // wave col base
    int grb = bm * 128 + wr * 64;               // wave row base

    if constexpr (EPI == 0 || EPI == 2) {
        __syncthreads();   // safe to reuse staging LDS
        u16* ep = (wave == 0) ? As0 : (wave == 1) ? Bs0 : (wave == 2) ? As1 : Bs1;
        int h = (gcolb >> 6) & 7;
        bool isK = (EPI == 2) || (gcolb < 512);
#pragma unroll
        for (int m = 0; m < 4; m++)
#pragma unroll
            for (int n = 0; n < 4; n++) {
                float bv = bias[gcolb + n * 16 + fr];
#pragma unroll
                for (int r = 0; r < 4; r++) {
                    int wq = m * 16 + g * 4 + r;     // row within quadrant
                    int wcc = n * 16 + fr;           // col within quadrant
                    float val = acc[m][n][r] + bv;
                    if constexpr (EPI == 2) {
                        // tanh-GELU: x * sigmoid(1.5957691*(x + 0.044715 x^3))
                        float xx = val;
                        float inner = fmaf(0.044715f * xx * xx, xx, xx);
                        float e = __expf(-1.5957691216f * inner);
                        val = xx * __builtin_amdgcn_rcpf(1.0f + e);
                    }
                    if (isK)
                        ep[wq * 64 + (wcc ^ ((wq & 7) << 3))] = f2bf(val);
                    else   // V: transpose in LDS -> [d][key]
                        ep[wcc * 64 + (wq ^ ((wcc & 7) << 3))] = f2bf(val);
                }
            }
#pragma unroll
        for (int rd = 0; rd < 8; rd++) {
            int row = rd * 8 + (lane >> 3);
            int ch = (lane & 7) ^ (row & 7);
            int4 v = *(const int4*)(ep + row * 64 + ch * 8);
            if constexpr (EPI == 2) {
                int grow = grb + row;
                *(int4*)(&((u16*)Cout)[(size_t)grow * Nn + gcolb + (lane & 7) * 8]) = v;
            } else {
                if (isK) {
                    int tok = grb + row;
                    int win = tok >> 9, key = tok & 511;
                    *(int4*)(&((u16*)Cout)[(((size_t)(win * 8 + h)) * 512 + key) * 64 + (lane & 7) * 8]) = v;
                } else {
                    int win = grb >> 9, key0 = grb & 511;   // 64 keys same window
                    *(int4*)(&((u16*)Cout2)[(((size_t)(win * 8 + h)) * 64 + row) * 512 + key0 + (lane & 7) * 8]) = v;
                }
            }
        }
    } else {
#pragma unroll
        for (int m = 0; m < 4; m++)
#pragma unroll
            for (int n = 0; n < 4; n++) {
                int col = gcolb + n * 16 + fr;
                float bv = bias[col];
#pragma unroll
                for (int r = 0; r < 4; r++) {
                    int row = grb + m * 16 + g * 4 + r;
                    float val = acc[m][n][r] + bv;
                    if constexpr (EPI == 1) {
                        int ri = win_to_img(row);
                        size_t o = (size_t)ri * 512 + col;
                        ((float*)Cout)[o] = val + resid[o];
                    } else {
                        size_t o = (size_t)row * 512 + col;
                        ((float*)Cout)[o] = val + resid[o];
                    }
                }
            }
    }
}

// Flash attention: 4096 blocks (XCD-chunk swizzled), 4 waves x 16 q-rows.
// kb:  bf16 [win][h][key 512][d 64]  (PLAIN)
// vtb: bf16 [win][h][d 64][key 512]  (PLAIN)
// Staging: global_load_lds w=16 with pre-swizzled SOURCE chunks (linear LDS
// dest); LDS content [row][c] = true[row][c^(row&7)], reads XOR-deswizzle.
// Ps is [64][64] XOR-swizzled (col ^ ((row&7)<<3)) -> 40KB LDS, 4 blocks/CU.
__global__ __launch_bounds__(256, 4) void k_attn(const u16* __restrict__ qb,
                                                 const u16* __restrict__ kb,
                                                 const u16* __restrict__ vtb,
                                                 u16* __restrict__ o) {
    __shared__ u16 K0[4096], K1[4096], V0[4096], V1[4096];  // [row 64][64]
    __shared__ u16 Ps[4096];                                 // [64][64] swizzled
    int bid = blockIdx.x;
    int wg = (bid & 7) * 512 + (bid >> 3);   // bijective XCD chunking (4096%8==0)
    int qc = wg & 7;
    int pair = wg >> 3;
    int hh = pair & 7, win = pair >> 3;
    int wave = threadIdx.x >> 6, lane = threadIdx.x & 63;
    const u16* kbw = kb + ((size_t)(win * 8 + hh)) * 512 * 64;
    const u16* vtw = vtb + ((size_t)(win * 8 + hh)) * 64 * 512;

    const u16* qrow = qb + ((size_t)hh * 512 + qc * 64 + (wave << 4) + (lane & 15)) * 64 + (lane >> 4) * 8;
    bfrag aq0 = *(const bfrag*)(qrow);
    bfrag aq1 = *(const bfrag*)(qrow + 32);

    ffrag acc[4] = {};
    float m_run[4], l_run[4];
#pragma unroll
    for (int r = 0; r < 4; r++) { m_run[r] = -1e30f; l_run[r] = 0.0f; }

    int srow = lane >> 3;                        // sub-row within 8-row group
    int sxo = ((lane & 7) ^ srow) * 8;           // pre-swizzled source chunk
    int fr = lane & 15;
    int fkc = lane >> 4;                         // logical k-chunk 0..3
    int kx0 = (fkc ^ (fr & 7)) * 8;              // physical chunk, k 0..31
    int kx1 = ((fkc + 4) ^ (fr & 7)) * 8;        // k 32..63
    int arow = (wave << 4) + fr;
    int pswz = (arow & 7) << 3;                  // Ps read swizzle (arow&7 == fr&7)

#define STAGE_KV(KS, VS, kc)                                                   \
    {                                                                          \
        GLOAD16(kbw + (size_t)((kc) * 64 + wave * 8 + srow) * 64 + sxo,        \
                KS + wave * 512);                                              \
        GLOAD16(kbw + (size_t)((kc) * 64 + 32 + wave * 8 + srow) * 64 + sxo,   \
                KS + 2048 + wave * 512);                                       \
        GLOAD16(vtw + (size_t)(wave * 8 + srow) * 512 + (kc) * 64 + sxo,       \
                VS + wave * 512);                                              \
        GLOAD16(vtw + (size_t)(32 + wave * 8 + srow) * 512 + (kc) * 64 + sxo,  \
                VS + 2048 + wave * 512);                                       \
    }
#define ATT_COMPUTE(KS, VS)                                                    \
    {                                                                          \
        ffrag s[4] = {};                                                       \
        _Pragma("unroll") for (int j = 0; j < 4; j++) {                        \
            bfrag b0 = *(const bfrag*)(KS + (j * 16 + fr) * 64 + kx0);         \
            s[j] = __builtin_amdgcn_mfma_f32_16x16x32_bf16(aq0, b0, s[j], 0, 0, 0); \
            bfrag b1 = *(const bfrag*)(KS + (j * 16 + fr) * 64 + kx1);         \
            s[j] = __builtin_amdgcn_mfma_f32_16x16x32_bf16(aq1, b1, s[j], 0, 0, 0); \
        }                                                                      \
        _Pragma("unroll") for (int r = 0; r < 4; r++) {                        \
            float mx = fmaxf(fmaxf(s[0][r], s[1][r]), fmaxf(s[2][r], s[3][r]));\
            _Pragma("unroll") for (int d = 1; d < 16; d <<= 1)                 \
                mx = fmaxf(mx, __shfl_xor(mx, d));                             \
            float mnew = fmaxf(m_run[r], mx);                                  \
            float alpha = __expf(m_run[r] - mnew);                             \
            m_run[r] = mnew;                                                   \
            float rs = 0.0f;                                                   \
            _Pragma("unroll") for (int j = 0; j < 4; j++) {                    \
                float p = __expf(s[j][r] - mnew);                              \
                s[j][r] = p;                                                   \
                rs += p;                                                       \
            }                                                                  \
            _Pragma("unroll") for (int d = 1; d < 16; d <<= 1)                 \
                rs += __shfl_xor(rs, d);                                       \
            l_run[r] = l_run[r] * alpha + rs;                                  \
            _Pragma("unroll") for (int j = 0; j < 4; j++) acc[j][r] *= alpha;  \
        }                                                                      \
        _Pragma("unroll") for (int j = 0; j < 4; j++)                          \
            _Pragma("unroll") for (int r = 0; r < 4; r++) {                    \
                int prow = (wave << 4) + (lane >> 4) * 4 + r;                  \
                Ps[prow * 64 + ((j * 16 + fr) ^ ((prow & 7) << 3))] = f2bf(s[j][r]); \
            }                                                                  \
        bfrag ap0 = *(const bfrag*)(&Ps[arow * 64 + ((fkc * 8) ^ pswz)]);      \
        bfrag ap1 = *(const bfrag*)(&Ps[arow * 64 + ((32 + fkc * 8) ^ pswz)]); \
        _Pragma("unroll") for (int j = 0; j < 4; j++) {                        \
            bfrag v0 = *(const bfrag*)(VS + (j * 16 + fr) * 64 + kx0);         \
            acc[j] = __builtin_amdgcn_mfma_f32_16x16x32_bf16(ap0, v0, acc[j], 0, 0, 0); \
            bfrag v1 = *(const bfrag*)(VS + (j * 16 + fr) * 64 + kx1);         \
            acc[j] = __builtin_amdgcn_mfma_f32_16x16x32_bf16(ap1, v1, acc[j], 0, 0, 0); \
        }                                                                      \
    }

    STAGE_KV(K0, V0, 0);
    __syncthreads();
#pragma unroll 1
    for (int kc = 0; kc < 8; kc += 2) {
        if (kc + 1 < 8) STAGE_KV(K1, V1, kc + 1);
        ATT_COMPUTE(K0, V0);
        __syncthreads();
        if (kc + 2 < 8) STAGE_KV(K0, V0, kc + 2);
        ATT_COMPUTE(K1, V1);
        __syncthreads();
    }
#undef STAGE_KV
#undef ATT_COMPUTE

    int row0 = qc * 64 + (wave << 4) + (lane >> 4) * 4;
#pragma unroll
    for (int j = 0; j < 4; j++) {
        int col = hh * 64 + j * 16 + fr;
#pragma unroll
        for (int r = 0; r < 4; r++) {
            float val = acc[j][r] / l_run[r];
            o[((size_t)win * 512 + row0 + r) * 512 + col] = f2bf(val);
        }
    }
}

extern "C" void kernel_launch(void* const* d_in, const int* in_sizes, int n_in,
                              void* d_out, int out_size, void* d_ws, size_t ws_size,
                              hipStream_t stream) {
    const float* x      = (const float*)d_in[0];
    const float* q_ms   = (const float*)d_in[1];
    const float* n1w    = (const float*)d_in[2];
    const float* n1b    = (const float*)d_in[3];
    const float* kv_w   = (const float*)d_in[4];
    const float* kv_b   = (const float*)d_in[5];
    const float* proj_w = (const float*)d_in[6];
    const float* proj_b = (const float*)d_in[7];
    const float* n2w    = (const float*)d_in[8];
    const float* n2b    = (const float*)d_in[9];
    const float* fc1_w  = (const float*)d_in[10];
    const float* fc1_b  = (const float*)d_in[11];
    const float* fc2_w  = (const float*)d_in[12];
    const float* fc2_b  = (const float*)d_in[13];

    char* ws = (char*)d_ws;
    const size_t OFF_XNW = 0;           // bf16 [32768][512]   33,554,432 B
    const size_t OFF_KB  = 33554432;    // bf16 [64][8][512][64]  33,554,432 B
    const size_t OFF_VT  = 67108864;    // bf16 [64][8][64][512]  33,554,432 B
    const size_t OFF_O   = 100663296;   // bf16 [32768][512]   33,554,432 B
    const size_t OFF_HID = 0;           // bf16 [32768][2048] (aliases dead bufs)
    const size_t OFF_X1  = 134217728;   // f32  [32768][512]   67,108,864 B
    const size_t OFF_XN2 = 201326592;   // bf16 [32768][512]   33,554,432 B
    const size_t OFF_W   = 234881024;   // transposed weights + q
    u16* xnw = (u16*)(ws + OFF_XNW);
    u16* kbb = (u16*)(ws + OFF_KB);
    u16* vtb = (u16*)(ws + OFF_VT);
    u16* ob  = (u16*)(ws + OFF_O);
    u16* hid = (u16*)(ws + OFF_HID);
    float* x1 = (float*)(ws + OFF_X1);
    u16* xn2 = (u16*)(ws + OFF_XN2);
    u16* kv_wt   = (u16*)(ws + OFF_W);        // [1024][512]
    u16* proj_wt = kv_wt + 512 * 1024;        // [512][512]
    u16* fc1_wt  = proj_wt + 512 * 512;       // [2048][512]
    u16* fc2_wt  = fc1_wt + 512 * 2048;       // [512][2048]
    u16* qbf     = fc2_wt + 2048 * 512;       // [8][512][64]
    size_t need = OFF_W + (size_t)(512 * 1024 + 512 * 512 + 512 * 2048 + 2048 * 512 + 8 * 512 * 64) * 2;
    if (ws_size < need) return;

    k_ln<<<8192, 256, 0, stream>>>(x, n1w, n1b, xnw, 1);
    k_prep<<<12288, 256, 0, stream>>>(kv_w, proj_w, fc1_w, fc2_w, q_ms,
                                      kv_wt, proj_wt, fc1_wt, fc2_wt, qbf);

    k_gemm128<0><<<2048, 256, 0, stream>>>(xnw, kv_wt, kv_b, kbb, 512, 1024, nullptr, vtb);
    k_attn<<<dim3(4096), 256, 0, stream>>>(qbf, kbb, vtb, ob);
    k_gemm128<1><<<1024, 256, 0, stream>>>(ob, proj_wt, proj_b, x1, 512, 512, x, nullptr);
    k_ln<<<8192, 256, 0, stream>>>(x1, n2w, n2b, xn2, 0);
    k_gemm128<2><<<4096, 256, 0, stream>>>(xn2, fc1_wt, fc1_b, hid, 512, 2048, nullptr, nullptr);
    k_gemm128<3><<<1024, 256, 0, stream>>>(hid, fc2_wt, fc2_b, d_out, 2048, 512, x1, nullptr);
}

// Round 16
// 437.935 us; speedup vs baseline: 1.7878x; 1.0285x over previous
//
#include <hip/hip_runtime.h>

typedef unsigned short u16;
typedef __attribute__((ext_vector_type(8))) short bfrag;   // 8 x bf16
typedef __attribute__((ext_vector_type(4))) float ffrag;   // 4 x f32

#define LN_EPS 1e-5f

#define GLOAD16(g, l)                                                          \
    __builtin_amdgcn_global_load_lds(                                          \
        (const __attribute__((address_space(1))) void*)(g),                    \
        (__attribute__((address_space(3))) void*)(l), 16, 0, 0)

__device__ __forceinline__ u16 f2bf(float f) {
    unsigned u = __builtin_bit_cast(unsigned, f);
    u += 0x7fffu + ((u >> 16) & 1u);   // RNE
    return (u16)(u >> 16);
}

// windowed token index -> image row index
__device__ __forceinline__ int win_to_img(int tok) {
    int win = tok >> 9, n = tok & 511;
    int wh = win >> 4, ww = (win >> 2) & 3, wd = win & 3;
    int ph = n >> 6, pw = (n >> 3) & 7, pd = n & 7;
    return ((wh * 8 + ph) * 32 + (ww * 8 + pw)) * 32 + (wd * 8 + pd);
}

// LayerNorm over C=512, one wave per token.
__global__ __launch_bounds__(256) void k_ln(const float* __restrict__ x,
                                            const float* __restrict__ w,
                                            const float* __restrict__ b,
                                            u16* __restrict__ out, int windowed) {
    int wave = threadIdx.x >> 6, lane = threadIdx.x & 63;
    int tok = blockIdx.x * 4 + wave;
    int src = windowed ? win_to_img(tok) : tok;
    const float* xr = x + (size_t)src * 512;
    float v[8];
#pragma unroll
    for (int i = 0; i < 2; i++) {
        float4 f = *(const float4*)(xr + i * 256 + lane * 4);
        v[i * 4 + 0] = f.x; v[i * 4 + 1] = f.y; v[i * 4 + 2] = f.z; v[i * 4 + 3] = f.w;
    }
    float s = 0.f;
#pragma unroll
    for (int i = 0; i < 8; i++) s += v[i];
#pragma unroll
    for (int m = 1; m < 64; m <<= 1) s += __shfl_xor(s, m);
    float mean = s * (1.0f / 512.0f);
    float vs = 0.f;
#pragma unroll
    for (int i = 0; i < 8; i++) { float d = v[i] - mean; vs += d * d; }
#pragma unroll
    for (int m = 1; m < 64; m <<= 1) vs += __shfl_xor(vs, m);
    float rstd = rsqrtf(vs * (1.0f / 512.0f) + LN_EPS);
    u16* orow = out + (size_t)tok * 512;
#pragma unroll
    for (int i = 0; i < 2; i++) {
        int c0 = i * 256 + lane * 4;
        ushort4 o;
        o.x = f2bf((v[i * 4 + 0] - mean) * rstd * w[c0 + 0] + b[c0 + 0]);
        o.y = f2bf((v[i * 4 + 1] - mean) * rstd * w[c0 + 1] + b[c0 + 1]);
        o.z = f2bf((v[i * 4 + 2] - mean) * rstd * w[c0 + 2] + b[c0 + 2]);
        o.w = f2bf((v[i * 4 + 3] - mean) * rstd * w[c0 + 3] + b[c0 + 3]);
        *(ushort4*)(orow + c0) = o;
    }
}

// Merged prep: 4 weight transposes (f32 [K][N] -> bf16 [N][K]) + q scale/cast.
__global__ __launch_bounds__(256) void k_prep(const float* __restrict__ kv_w,
                                              const float* __restrict__ proj_w,
                                              const float* __restrict__ fc1_w,
                                              const float* __restrict__ fc2_w,
                                              const float* __restrict__ q,
                                              u16* __restrict__ kv_wt,
                                              u16* __restrict__ proj_wt,
                                              u16* __restrict__ fc1_wt,
                                              u16* __restrict__ fc2_wt,
                                              u16* __restrict__ qbf) {
    int i = blockIdx.x * 256 + threadIdx.x;
    if (i < 524288) {                       // kv_wt [1024][512]
        int n = i >> 9, k = i & 511;
        kv_wt[i] = f2bf(kv_w[k * 1024 + n]);
    } else if (i < 786432) {                // proj_wt [512][512]
        int j = i - 524288, n = j >> 9, k = j & 511;
        proj_wt[j] = f2bf(proj_w[k * 512 + n]);
    } else if (i < 1835008) {               // fc1_wt [2048][512]
        int j = i - 786432, n = j >> 9, k = j & 511;
        fc1_wt[j] = f2bf(fc1_w[k * 2048 + n]);
    } else if (i < 2883584) {               // fc2_wt [512][2048]
        int j = i - 1835008, n = j >> 11, k = j & 2047;
        fc2_wt[j] = f2bf(fc2_w[k * 512 + n]);
    } else {                                // qbf [8*512*64], pre-scaled
        int j = i - 2883584;
        qbf[j] = f2bf(q[j] * 0.125f);
    }
}

// ==== 128x128 GEMM, BK=32, 4 waves (2x2), 2-phase dbuf (R7-proven best) ====
// launch_bounds(256,4): 64 VGPR + 64 AGPR; (256,5) spilled (R11 post-mortem).
// EPI 2 GELU: tanh-form via sigmoid (R13: fc1 134->~105us).
template <int EPI>
__global__ __launch_bounds__(256, 4) void k_gemm128(const u16* __restrict__ A,
                                                    const u16* __restrict__ Bt,
                                                    const float* __restrict__ bias,
                                                    void* __restrict__ Cout, int K, int Nn,
                                                    const float* __restrict__ resid,
                                                    void* __restrict__ Cout2) {
    __shared__ u16 As0[4096], Bs0[4096], As1[4096], Bs1[4096];
    int tid = threadIdx.x;
    int wave = tid >> 6, lane = tid & 63;
    int wr = wave >> 1, wc = wave & 1;

    int gx = Nn >> 7;
    int nwg = gridDim.x;
    int wg = blockIdx.x;
    int wgs = (wg & 7) * (nwg >> 3) + (wg >> 3);   // XCD chunking (nwg%8==0)
    int bn = wgs % gx, bm = wgs / gx;

    int rt = wave * 32 + (lane >> 2);
    int sxo = ((lane & 3) ^ ((rt ^ (rt >> 2)) & 3)) * 8;
    const u16* Ag = A + (size_t)(bm * 128 + rt) * K + sxo;
    const u16* Bg = Bt + (size_t)(bn * 128 + rt) * K + sxo;

    int fr = lane & 15, g = lane >> 4;
    int pco = (g ^ ((fr ^ (fr >> 2)) & 3)) * 8;

    ffrag acc[4][4] = {};

#define STAGE(AS, BS, k0)                                                      \
    {                                                                          \
        GLOAD16(Ag + (k0), AS + wave * 1024);                                  \
        GLOAD16(Ag + (k0) + 16 * K, AS + wave * 1024 + 512);                   \
        GLOAD16(Bg + (k0), BS + wave * 1024);                                  \
        GLOAD16(Bg + (k0) + 16 * K, BS + wave * 1024 + 512);                   \
    }
#define COMPUTE(AS, BS)                                                        \
    {                                                                          \
        bfrag a[4], b[4];                                                      \
        _Pragma("unroll") for (int m = 0; m < 4; m++)                          \
            a[m] = *(const bfrag*)(AS + (wr * 64 + m * 16 + fr) * 32 + pco);   \
        _Pragma("unroll") for (int n = 0; n < 4; n++)                          \
            b[n] = *(const bfrag*)(BS + (wc * 64 + n * 16 + fr) * 32 + pco);   \
        _Pragma("unroll") for (int m = 0; m < 4; m++)                          \
            _Pragma("unroll") for (int n = 0; n < 4; n++)                      \
                acc[m][n] = __builtin_amdgcn_mfma_f32_16x16x32_bf16(           \
                    a[m], b[n], acc[m][n], 0, 0, 0);                           \
    }

    int nt = K >> 5;   // even for all our K
    STAGE(As0, Bs0, 0);
    __syncthreads();
    int t = 0;
    for (; t + 2 < nt; t += 2) {
        STAGE(As1, Bs1, (t + 1) * 32);
        COMPUTE(As0, Bs0);
        __syncthreads();
        STAGE(As0, Bs0, (t + 2) * 32);
        COMPUTE(As1, Bs1);
        __syncthreads();
    }
    STAGE(As1, Bs1, (nt - 1) * 32);
    COMPUTE(As0, Bs0);
    __syncthreads();
    COMPUTE(As1, Bs1);
#undef STAGE
#undef COMPUTE

    int gcolb = bn * 128 + wc * 64;             // wave col base
    int grb = bm * 128 + wr * 64;               // wave row base

    if constexpr (EPI == 0 || EPI == 2) {
        __syncthreads();   // safe to reuse staging LDS
        u16* ep = (wave == 0) ? As0 : (wave == 1) ? Bs0 : (wave == 2) ? As1 : Bs1;
        int h = (gcolb >> 6) & 7;
        bool isK = (EPI == 2) || (gcolb < 512);
#pragma unroll
        for (int m = 0; m < 4; m++)
#pragma unroll
            for (int n = 0; n < 4; n++) {
                float bv = bias[gcolb + n * 16 + fr];
#pragma unroll
                for (int r = 0; r < 4; r++) {
                    int wq = m * 16 + g * 4 + r;     // row within quadrant
                    int wcc = n * 16 + fr;           // col within quadrant
                    float val = acc[m][n][r] + bv;
                    if constexpr (EPI == 2) {
                        // tanh-GELU: x * sigmoid(1.5957691*(x + 0.044715 x^3))
                        float xx = val;
                        float inner = fmaf(0.044715f * xx * xx, xx, xx);
                        float e = __expf(-1.5957691216f * inner);
                        val = xx * __builtin_amdgcn_rcpf(1.0f + e);
                    }
                    if (isK)
                        ep[wq * 64 + (wcc ^ ((wq & 7) << 3))] = f2bf(val);
                    else   // V: transpose in LDS -> [d][key]
                        ep[wcc * 64 + (wq ^ ((wcc & 7) << 3))] = f2bf(val);
                }
            }
#pragma unroll
        for (int rd = 0; rd < 8; rd++) {
            int row = rd * 8 + (lane >> 3);
            int ch = (lane & 7) ^ (row & 7);
            int4 v = *(const int4*)(ep + row * 64 + ch * 8);
            if constexpr (EPI == 2) {
                int grow = grb + row;
                *(int4*)(&((u16*)Cout)[(size_t)grow * Nn + gcolb + (lane & 7) * 8]) = v;
            } else {
                if (isK) {
                    int tok = grb + row;
                    int win = tok >> 9, key = tok & 511;
                    *(int4*)(&((u16*)Cout)[(((size_t)(win * 8 + h)) * 512 + key) * 64 + (lane & 7) * 8]) = v;
                } else {
                    int win = grb >> 9, key0 = grb & 511;   // 64 keys same window
                    *(int4*)(&((u16*)Cout2)[(((size_t)(win * 8 + h)) * 64 + row) * 512 + key0 + (lane & 7) * 8]) = v;
                }
            }
        }
    } else {
#pragma unroll
        for (int m = 0; m < 4; m++)
#pragma unroll
            for (int n = 0; n < 4; n++) {
                int col = gcolb + n * 16 + fr;
                float bv = bias[col];
#pragma unroll
                for (int r = 0; r < 4; r++) {
                    int row = grb + m * 16 + g * 4 + r;
                    float val = acc[m][n][r] + bv;
                    if constexpr (EPI == 1) {
                        int ri = win_to_img(row);
                        size_t o = (size_t)ri * 512 + col;
                        ((float*)Cout)[o] = val + resid[o];
                    } else {
                        size_t o = (size_t)row * 512 + col;
                        ((float*)Cout)[o] = val + resid[o];
                    }
                }
            }
    }
}

// Flash attention (R13-proven dataflow + deferred max/sum bookkeeping).
// kb:  bf16 [win][h][key 512][d 64]  (PLAIN); vtb: bf16 [win][h][d 64][key 512].
// Staging: gload_lds w=16, pre-swizzled source chunks, reads XOR-deswizzle.
// Softmax (T13): common path = in-lane max check only (no shfl, no rescale);
// full 16-lane max-reduce + rescale only when some lane's tile max exceeds
// m_run[r]+8 (in-lane max bounds row max; p <= e^8 safe in bf16/f32).
// l_run[r] = lane-partial sum (alpha-rescaled on rare path); 16-lane reduce
// ONCE at the end. Ps relay identical to R13 (verified).
__global__ __launch_bounds__(256, 4) void k_attn(const u16* __restrict__ qb,
                                                 const u16* __restrict__ kb,
                                                 const u16* __restrict__ vtb,
                                                 u16* __restrict__ o) {
    __shared__ u16 K0[4096], K1[4096], V0[4096], V1[4096];  // [row 64][64]
    __shared__ u16 Ps[4096];                                 // [64][64] swizzled
    int bid = blockIdx.x;
    int wg = (bid & 7) * 512 + (bid >> 3);   // bijective XCD chunking (4096%8==0)
    int qc = wg & 7;
    int pair = wg >> 3;
    int hh = pair & 7, win = pair >> 3;
    int wave = threadIdx.x >> 6, lane = threadIdx.x & 63;
    const u16* kbw = kb + ((size_t)(win * 8 + hh)) * 512 * 64;
    const u16* vtw = vtb + ((size_t)(win * 8 + hh)) * 64 * 512;

    const u16* qrow = qb + ((size_t)hh * 512 + qc * 64 + (wave << 4) + (lane & 15)) * 64 + (lane >> 4) * 8;
    bfrag aq0 = *(const bfrag*)(qrow);
    bfrag aq1 = *(const bfrag*)(qrow + 32);

    ffrag acc[4] = {};
    float m_run[4], l_run[4];
#pragma unroll
    for (int r = 0; r < 4; r++) { m_run[r] = -1e30f; l_run[r] = 0.0f; }

    int srow = lane >> 3;                        // staging sub-row
    int sxo = ((lane & 7) ^ srow) * 8;           // pre-swizzled source chunk
    int fr = lane & 15;
    int fkc = lane >> 4;                         // logical k-chunk 0..3
    int kx0 = (fkc ^ (fr & 7)) * 8;              // physical chunk, k 0..31
    int kx1 = ((fkc + 4) ^ (fr & 7)) * 8;        // k 32..63
    int arow = (wave << 4) + fr;
    int pswz = (arow & 7) << 3;                  // Ps read swizzle (arow&7 == fr&7)

#define STAGE_KV(KS, VS, kc)                                                   \
    {                                                                          \
        GLOAD16(kbw + (size_t)((kc) * 64 + wave * 8 + srow) * 64 + sxo,        \
                KS + wave * 512);                                              \
        GLOAD16(kbw + (size_t)((kc) * 64 + 32 + wave * 8 + srow) * 64 + sxo,   \
                KS + 2048 + wave * 512);                                       \
        GLOAD16(vtw + (size_t)(wave * 8 + srow) * 512 + (kc) * 64 + sxo,       \
                VS + wave * 512);                                              \
        GLOAD16(vtw + (size_t)(32 + wave * 8 + srow) * 512 + (kc) * 64 + sxo,  \
                VS + 2048 + wave * 512);                                       \
    }
#define ATT_COMPUTE(KS, VS)                                                    \
    {                                                                          \
        ffrag s[4] = {};                                                       \
        _Pragma("unroll") for (int j = 0; j < 4; j++) {                        \
            bfrag b0 = *(const bfrag*)(KS + (j * 16 + fr) * 64 + kx0);         \
            s[j] = __builtin_amdgcn_mfma_f32_16x16x32_bf16(aq0, b0, s[j], 0, 0, 0); \
            bfrag b1 = *(const bfrag*)(KS + (j * 16 + fr) * 64 + kx1);         \
            s[j] = __builtin_amdgcn_mfma_f32_16x16x32_bf16(aq1, b1, s[j], 0, 0, 0); \
        }                                                                      \
        int need = 0;                                                          \
        _Pragma("unroll") for (int r = 0; r < 4; r++) {                        \
            float mxj = fmaxf(fmaxf(s[0][r], s[1][r]),                         \
                              fmaxf(s[2][r], s[3][r]));                        \
            need |= (mxj > m_run[r] + 8.0f) ? 1 : 0;                           \
        }                                                                      \
        if (__any(need)) {                                                     \
            _Pragma("unroll") for (int r = 0; r < 4; r++) {                    \
                float mx = fmaxf(fmaxf(s[0][r], s[1][r]),                      \
                                 fmaxf(s[2][r], s[3][r]));                     \
                _Pragma("unroll") for (int d = 1; d < 16; d <<= 1)             \
                    mx = fmaxf(mx, __shfl_xor(mx, d));                         \
                float mnew = fmaxf(m_run[r], mx);                              \
                float alpha = __expf(m_run[r] - mnew);                         \
                m_run[r] = mnew;                                               \
                l_run[r] *= alpha;                                             \
                _Pragma("unroll") for (int j = 0; j < 4; j++)                  \
                    acc[j][r] *= alpha;                                        \
            }                                                                  \
        }                                                                      \
        _Pragma("unroll") for (int j = 0; j < 4; j++)                          \
            _Pragma("unroll") for (int r = 0; r < 4; r++) {                    \
                float p = __expf(s[j][r] - m_run[r]);                          \
                l_run[r] += p;                                                 \
                int prow = (wave << 4) + (lane >> 4) * 4 + r;                  \
                Ps[prow * 64 + ((j * 16 + fr) ^ ((prow & 7) << 3))] = f2bf(p); \
            }                                                                  \
        bfrag ap0 = *(const bfrag*)(&Ps[arow * 64 + ((fkc * 8) ^ pswz)]);      \
        bfrag ap1 = *(const bfrag*)(&Ps[arow * 64 + ((32 + fkc * 8) ^ pswz)]); \
        _Pragma("unroll") for (int j = 0; j < 4; j++) {                        \
            bfrag v0 = *(const bfrag*)(VS + (j * 16 + fr) * 64 + kx0);         \
            acc[j] = __builtin_amdgcn_mfma_f32_16x16x32_bf16(ap0, v0, acc[j], 0, 0, 0); \
            bfrag v1 = *(const bfrag*)(VS + (j * 16 + fr) * 64 + kx1);         \
            acc[j] = __builtin_amdgcn_mfma_f32_16x16x32_bf16(ap1, v1, acc[j], 0, 0, 0); \
        }                                                                      \
    }

    STAGE_KV(K0, V0, 0);
    __syncthreads();
#pragma unroll 1
    for (int kc = 0; kc < 8; kc += 2) {
        if (kc + 1 < 8) STAGE_KV(K1, V1, kc + 1);
        ATT_COMPUTE(K0, V0);
        __syncthreads();
        if (kc + 2 < 8) STAGE_KV(K0, V0, kc + 2);
        ATT_COMPUTE(K1, V1);
        __syncthreads();
    }
#undef STAGE_KV
#undef ATT_COMPUTE

    // deferred sum-reduce: lane partials -> full row sums (once)
#pragma unroll
    for (int r = 0; r < 4; r++) {
#pragma unroll
        for (int d = 1; d < 16; d <<= 1)
            l_run[r] += __shfl_xor(l_run[r], d);
    }

    int row0 = qc * 64 + (wave << 4) + (lane >> 4) * 4;
#pragma unroll
    for (int j = 0; j < 4; j++) {
        int col = hh * 64 + j * 16 + fr;
#pragma unroll
        for (int r = 0; r < 4; r++) {
            float val = acc[j][r] / l_run[r];
            o[((size_t)win * 512 + row0 + r) * 512 + col] = f2bf(val);
        }
    }
}

extern "C" void kernel_launch(void* const* d_in, const int* in_sizes, int n_in,
                              void* d_out, int out_size, void* d_ws, size_t ws_size,
                              hipStream_t stream) {
    const float* x      = (const float*)d_in[0];
    const float* q_ms   = (const float*)d_in[1];
    const float* n1w    = (const float*)d_in[2];
    const float* n1b    = (const float*)d_in[3];
    const float* kv_w   = (const float*)d_in[4];
    const float* kv_b   = (const float*)d_in[5];
    const float* proj_w = (const float*)d_in[6];
    const float* proj_b = (const float*)d_in[7];
    const float* n2w    = (const float*)d_in[8];
    const float* n2b    = (const float*)d_in[9];
    const float* fc1_w  = (const float*)d_in[10];
    const float* fc1_b  = (const float*)d_in[11];
    const float* fc2_w  = (const float*)d_in[12];
    const float* fc2_b  = (const float*)d_in[13];

    char* ws = (char*)d_ws;
    const size_t OFF_XNW = 0;           // bf16 [32768][512]   33,554,432 B
    const size_t OFF_KB  = 33554432;    // bf16 [64][8][512][64]  33,554,432 B
    const size_t OFF_VT  = 67108864;    // bf16 [64][8][64][512]  33,554,432 B
    const size_t OFF_O   = 100663296;   // bf16 [32768][512]   33,554,432 B
    const size_t OFF_HID = 0;           // bf16 [32768][2048] (aliases dead bufs)
    const size_t OFF_X1  = 134217728;   // f32  [32768][512]   67,108,864 B
    const size_t OFF_XN2 = 201326592;   // bf16 [32768][512]   33,554,432 B
    const size_t OFF_W   = 234881024;   // transposed weights + q
    u16* xnw = (u16*)(ws + OFF_XNW);
    u16* kbb = (u16*)(ws + OFF_KB);
    u16* vtb = (u16*)(ws + OFF_VT);
    u16* ob  = (u16*)(ws + OFF_O);
    u16* hid = (u16*)(ws + OFF_HID);
    float* x1 = (float*)(ws + OFF_X1);
    u16* xn2 = (u16*)(ws + OFF_XN2);
    u16* kv_wt   = (u16*)(ws + OFF_W);        // [1024][512]
    u16* proj_wt = kv_wt + 512 * 1024;        // [512][512]
    u16* fc1_wt  = proj_wt + 512 * 512;       // [2048][512]
    u16* fc2_wt  = fc1_wt + 512 * 2048;       // [512][2048]
    u16* qbf     = fc2_wt + 2048 * 512;       // [8][512][64]
    size_t need = OFF_W + (size_t)(512 * 1024 + 512 * 512 + 512 * 2048 + 2048 * 512 + 8 * 512 * 64) * 2;
    if (ws_size < need) return;

    k_ln<<<8192, 256, 0, stream>>>(x, n1w, n1b, xnw, 1);
    k_prep<<<12288, 256, 0, stream>>>(kv_w, proj_w, fc1_w, fc2_w, q_ms,
                                      kv_wt, proj_wt, fc1_wt, fc2_wt, qbf);

    k_gemm128<0><<<2048, 256, 0, stream>>>(xnw, kv_wt, kv_b, kbb, 512, 1024, nullptr, vtb);
    k_attn<<<dim3(4096), 256, 0, stream>>>(qbf, kbb, vtb, ob);
    k_gemm128<1><<<1024, 256, 0, stream>>>(ob, proj_wt, proj_b, x1, 512, 512, x, nullptr);
    k_ln<<<8192, 256, 0, stream>>>(x1, n2w, n2b, xn2, 0);
    k_gemm128<2><<<4096, 256, 0, stream>>>(xn2, fc1_wt, fc1_b, hid, 512, 2048, nullptr, nullptr);
    k_gemm128<3><<<1024, 256, 0, stream>>>(hid, fc2_wt, fc2_b, d_out, 2048, 512, x1, nullptr);
}

// Round 17
// 414.802 us; speedup vs baseline: 1.8875x; 1.0558x over previous
//
#include <hip/hip_runtime.h>

typedef unsigned short u16;
typedef __attribute__((ext_vector_type(8))) short bfrag;   // 8 x bf16
typedef __attribute__((ext_vector_type(4))) float ffrag;   // 4 x f32

#define LN_EPS 1e-5f

#define GLOAD16(g, l)                                                          \
    __builtin_amdgcn_global_load_lds(                                          \
        (const __attribute__((address_space(1))) void*)(g),                    \
        (__attribute__((address_space(3))) void*)(l), 16, 0, 0)

__device__ __forceinline__ u16 f2bf(float f) {
    unsigned u = __builtin_bit_cast(unsigned, f);
    u += 0x7fffu + ((u >> 16) & 1u);   // RNE
    return (u16)(u >> 16);
}

// windowed token index -> image row index
__device__ __forceinline__ int win_to_img(int tok) {
    int win = tok >> 9, n = tok & 511;
    int wh = win >> 4, ww = (win >> 2) & 3, wd = win & 3;
    int ph = n >> 6, pw = (n >> 3) & 7, pd = n & 7;
    return ((wh * 8 + ph) * 32 + (ww * 8 + pw)) * 32 + (wd * 8 + pd);
}

// LayerNorm over C=512, one wave per token.
__global__ __launch_bounds__(256) void k_ln(const float* __restrict__ x,
                                            const float* __restrict__ w,
                                            const float* __restrict__ b,
                                            u16* __restrict__ out, int windowed) {
    int wave = threadIdx.x >> 6, lane = threadIdx.x & 63;
    int tok = blockIdx.x * 4 + wave;
    int src = windowed ? win_to_img(tok) : tok;
    const float* xr = x + (size_t)src * 512;
    float v[8];
#pragma unroll
    for (int i = 0; i < 2; i++) {
        float4 f = *(const float4*)(xr + i * 256 + lane * 4);
        v[i * 4 + 0] = f.x; v[i * 4 + 1] = f.y; v[i * 4 + 2] = f.z; v[i * 4 + 3] = f.w;
    }
    float s = 0.f;
#pragma unroll
    for (int i = 0; i < 8; i++) s += v[i];
#pragma unroll
    for (int m = 1; m < 64; m <<= 1) s += __shfl_xor(s, m);
    float mean = s * (1.0f / 512.0f);
    float vs = 0.f;
#pragma unroll
    for (int i = 0; i < 8; i++) { float d = v[i] - mean; vs += d * d; }
#pragma unroll
    for (int m = 1; m < 64; m <<= 1) vs += __shfl_xor(vs, m);
    float rstd = rsqrtf(vs * (1.0f / 512.0f) + LN_EPS);
    u16* orow = out + (size_t)tok * 512;
#pragma unroll
    for (int i = 0; i < 2; i++) {
        int c0 = i * 256 + lane * 4;
        ushort4 o;
        o.x = f2bf((v[i * 4 + 0] - mean) * rstd * w[c0 + 0] + b[c0 + 0]);
        o.y = f2bf((v[i * 4 + 1] - mean) * rstd * w[c0 + 1] + b[c0 + 1]);
        o.z = f2bf((v[i * 4 + 2] - mean) * rstd * w[c0 + 2] + b[c0 + 2]);
        o.w = f2bf((v[i * 4 + 3] - mean) * rstd * w[c0 + 3] + b[c0 + 3]);
        *(ushort4*)(orow + c0) = o;
    }
}

// Merged prep: 4 weight transposes (f32 [K][N] -> bf16 [N][K]) + q scale/cast.
__global__ __launch_bounds__(256) void k_prep(const float* __restrict__ kv_w,
                                              const float* __restrict__ proj_w,
                                              const float* __restrict__ fc1_w,
                                              const float* __restrict__ fc2_w,
                                              const float* __restrict__ q,
                                              u16* __restrict__ kv_wt,
                                              u16* __restrict__ proj_wt,
                                              u16* __restrict__ fc1_wt,
                                              u16* __restrict__ fc2_wt,
                                              u16* __restrict__ qbf) {
    int i = blockIdx.x * 256 + threadIdx.x;
    if (i < 524288) {                       // kv_wt [1024][512]
        int n = i >> 9, k = i & 511;
        kv_wt[i] = f2bf(kv_w[k * 1024 + n]);
    } else if (i < 786432) {                // proj_wt [512][512]
        int j = i - 524288, n = j >> 9, k = j & 511;
        proj_wt[j] = f2bf(proj_w[k * 512 + n]);
    } else if (i < 1835008) {               // fc1_wt [2048][512]
        int j = i - 786432, n = j >> 9, k = j & 511;
        fc1_wt[j] = f2bf(fc1_w[k * 2048 + n]);
    } else if (i < 2883584) {               // fc2_wt [512][2048]
        int j = i - 1835008, n = j >> 11, k = j & 2047;
        fc2_wt[j] = f2bf(fc2_w[k * 512 + n]);
    } else {                                // qbf [8*512*64], pre-scaled
        int j = i - 2883584;
        qbf[j] = f2bf(q[j] * 0.125f);
    }
}

// ==== 128x128 GEMM, BK=32, 4 waves (2x2), 2-phase dbuf (R7-proven best) ====
// launch_bounds(256,4): 64 VGPR + 64 AGPR; (256,5) spilled (R11 post-mortem).
// Used for kv/proj/fc1 (A operand is L2/L3-resident; 2-phase covers latency).
template <int EPI>
__global__ __launch_bounds__(256, 4) void k_gemm128(const u16* __restrict__ A,
                                                    const u16* __restrict__ Bt,
                                                    const float* __restrict__ bias,
                                                    void* __restrict__ Cout, int K, int Nn,
                                                    const float* __restrict__ resid,
                                                    void* __restrict__ Cout2) {
    __shared__ u16 As0[4096], Bs0[4096], As1[4096], Bs1[4096];
    int tid = threadIdx.x;
    int wave = tid >> 6, lane = tid & 63;
    int wr = wave >> 1, wc = wave & 1;

    int gx = Nn >> 7;
    int nwg = gridDim.x;
    int wg = blockIdx.x;
    int wgs = (wg & 7) * (nwg >> 3) + (wg >> 3);   // XCD chunking (nwg%8==0)
    int bn = wgs % gx, bm = wgs / gx;

    int rt = wave * 32 + (lane >> 2);
    int sxo = ((lane & 3) ^ ((rt ^ (rt >> 2)) & 3)) * 8;
    const u16* Ag = A + (size_t)(bm * 128 + rt) * K + sxo;
    const u16* Bg = Bt + (size_t)(bn * 128 + rt) * K + sxo;

    int fr = lane & 15, g = lane >> 4;
    int pco = (g ^ ((fr ^ (fr >> 2)) & 3)) * 8;

    ffrag acc[4][4] = {};

#define STAGE(AS, BS, k0)                                                      \
    {                                                                          \
        GLOAD16(Ag + (k0), AS + wave * 1024);                                  \
        GLOAD16(Ag + (k0) + 16 * K, AS + wave * 1024 + 512);                   \
        GLOAD16(Bg + (k0), BS + wave * 1024);                                  \
        GLOAD16(Bg + (k0) + 16 * K, BS + wave * 1024 + 512);                   \
    }
#define COMPUTE(AS, BS)                                                        \
    {                                                                          \
        bfrag a[4], b[4];                                                      \
        _Pragma("unroll") for (int m = 0; m < 4; m++)                          \
            a[m] = *(const bfrag*)(AS + (wr * 64 + m * 16 + fr) * 32 + pco);   \
        _Pragma("unroll") for (int n = 0; n < 4; n++)                          \
            b[n] = *(const bfrag*)(BS + (wc * 64 + n * 16 + fr) * 32 + pco);   \
        _Pragma("unroll") for (int m = 0; m < 4; m++)                          \
            _Pragma("unroll") for (int n = 0; n < 4; n++)                      \
                acc[m][n] = __builtin_amdgcn_mfma_f32_16x16x32_bf16(           \
                    a[m], b[n], acc[m][n], 0, 0, 0);                           \
    }

    int nt = K >> 5;   // even for all our K
    STAGE(As0, Bs0, 0);
    __syncthreads();
    int t = 0;
    for (; t + 2 < nt; t += 2) {
        STAGE(As1, Bs1, (t + 1) * 32);
        COMPUTE(As0, Bs0);
        __syncthreads();
        STAGE(As0, Bs0, (t + 2) * 32);
        COMPUTE(As1, Bs1);
        __syncthreads();
    }
    STAGE(As1, Bs1, (nt - 1) * 32);
    COMPUTE(As0, Bs0);
    __syncthreads();
    COMPUTE(As1, Bs1);
#undef STAGE
#undef COMPUTE

    int gcolb = bn * 128 + wc * 64;             // wave col base
    int grb = bm * 128 + wr * 64;               // wave row base

    if constexpr (EPI == 0 || EPI == 2) {
        __syncthreads();   // safe to reuse staging LDS
        u16* ep = (wave == 0) ? As0 : (wave == 1) ? Bs0 : (wave == 2) ? As1 : Bs1;
        int h = (gcolb >> 6) & 7;
        bool isK = (EPI == 2) || (gcolb < 512);
#pragma unroll
        for (int m = 0; m < 4; m++)
#pragma unroll
            for (int n = 0; n < 4; n++) {
                float bv = bias[gcolb + n * 16 + fr];
#pragma unroll
                for (int r = 0; r < 4; r++) {
                    int wq = m * 16 + g * 4 + r;     // row within quadrant
                    int wcc = n * 16 + fr;           // col within quadrant
                    float val = acc[m][n][r] + bv;
                    if constexpr (EPI == 2) {
                        // tanh-GELU: x * sigmoid(1.5957691*(x + 0.044715 x^3))
                        float xx = val;
                        float inner = fmaf(0.044715f * xx * xx, xx, xx);
                        float e = __expf(-1.5957691216f * inner);
                        val = xx * __builtin_amdgcn_rcpf(1.0f + e);
                    }
                    if (isK)
                        ep[wq * 64 + (wcc ^ ((wq & 7) << 3))] = f2bf(val);
                    else   // V: transpose in LDS -> [d][key]
                        ep[wcc * 64 + (wq ^ ((wcc & 7) << 3))] = f2bf(val);
                }
            }
#pragma unroll
        for (int rd = 0; rd < 8; rd++) {
            int row = rd * 8 + (lane >> 3);
            int ch = (lane & 7) ^ (row & 7);
            int4 v = *(const int4*)(ep + row * 64 + ch * 8);
            if constexpr (EPI == 2) {
                int grow = grb + row;
                *(int4*)(&((u16*)Cout)[(size_t)grow * Nn + gcolb + (lane & 7) * 8]) = v;
            } else {
                if (isK) {
                    int tok = grb + row;
                    int win = tok >> 9, key = tok & 511;
                    *(int4*)(&((u16*)Cout)[(((size_t)(win * 8 + h)) * 512 + key) * 64 + (lane & 7) * 8]) = v;
                } else {
                    int win = grb >> 9, key0 = grb & 511;   // 64 keys same window
                    *(int4*)(&((u16*)Cout2)[(((size_t)(win * 8 + h)) * 64 + row) * 512 + key0 + (lane & 7) * 8]) = v;
                }
            }
        }
    } else {
#pragma unroll
        for (int m = 0; m < 4; m++)
#pragma unroll
            for (int n = 0; n < 4; n++) {
                int col = gcolb + n * 16 + fr;
                float bv = bias[col];
#pragma unroll
                for (int r = 0; r < 4; r++) {
                    int row = grb + m * 16 + g * 4 + r;
                    float val = acc[m][n][r] + bv;
                    if constexpr (EPI == 1) {
                        int ri = win_to_img(row);
                        size_t o = (size_t)ri * 512 + col;
                        ((float*)Cout)[o] = val + resid[o];
                    } else {
                        size_t o = (size_t)row * 512 + col;
                        ((float*)Cout)[o] = val + resid[o];
                    }
                }
            }
    }
}

// ==== fc2 GEMM: 128x128, BK=32, DEPTH-4 counted-vmcnt ring (R10-proven form,
// one more slot). fc2's A (hid, 134MB) streams from HBM (~900cyc); 2-phase
// only hides ~250cyc (R16 PMC: 1030cyc/kstep vs 310 MFMA). Depth-4 gives
// issue-to-wait = 3 phases. vmcnt ledger: steady 12 outstanding -> vmcnt(8)
// retires exactly tile t+1; tails 8->vmcnt(4), 4->vmcnt(0). WAR: slot
// (t+3)&3 last ds_read at COMPUTE(t-1), lgkm-drained before that barrier.
// 64KB LDS -> 2 blocks/CU; deep pipeline replaces the lost TLP.
// Epilogue: +bias, + resid(x1) -> f32 (direct stores, no LDS reuse).
__global__ __launch_bounds__(256, 2) void k_gemm128d4(const u16* __restrict__ A,
                                                      const u16* __restrict__ Bt,
                                                      const float* __restrict__ bias,
                                                      float* __restrict__ Cout, int K, int Nn,
                                                      const float* __restrict__ resid) {
    __shared__ u16 sm[32768];   // 4 slots x 8192 u16 (A @0, B @4096 per slot)
    int tid = threadIdx.x;
    int wave = tid >> 6, lane = tid & 63;
    int wr = wave >> 1, wc = wave & 1;

    int gx = Nn >> 7;
    int nwg = gridDim.x;
    int wg = blockIdx.x;
    int wgs = (wg & 7) * (nwg >> 3) + (wg >> 3);   // XCD chunking (nwg%8==0)
    int bn = wgs % gx, bm = wgs / gx;

    int rt = wave * 32 + (lane >> 2);
    int sxo = ((lane & 3) ^ ((rt ^ (rt >> 2)) & 3)) * 8;
    const u16* Ag = A + (size_t)(bm * 128 + rt) * K + sxo;
    const u16* Bg = Bt + (size_t)(bn * 128 + rt) * K + sxo;
    int wl = wave * 1024;

    int fr = lane & 15, g = lane >> 4;
    int pco = (g ^ ((fr ^ (fr >> 2)) & 3)) * 8;

    ffrag acc[4][4] = {};

#define STAGE4(SLOT, k0)                                                       \
    {                                                                          \
        u16* d = sm + (SLOT) * 8192 + wl;                                      \
        GLOAD16(Ag + (k0), d);                                                 \
        GLOAD16(Ag + (k0) + 16 * K, d + 512);                                  \
        GLOAD16(Bg + (k0), d + 4096);                                          \
        GLOAD16(Bg + (k0) + 16 * K, d + 4608);                                 \
    }
#define COMPUTE4(SLOT)                                                         \
    {                                                                          \
        const u16* Ab = sm + (SLOT) * 8192;                                    \
        const u16* Bb = Ab + 4096;                                             \
        bfrag a[4], b[4];                                                      \
        _Pragma("unroll") for (int m = 0; m < 4; m++)                          \
            a[m] = *(const bfrag*)(Ab + (wr * 64 + m * 16 + fr) * 32 + pco);   \
        _Pragma("unroll") for (int n = 0; n < 4; n++)                          \
            b[n] = *(const bfrag*)(Bb + (wc * 64 + n * 16 + fr) * 32 + pco);   \
        __builtin_amdgcn_s_setprio(1);                                         \
        _Pragma("unroll") for (int m = 0; m < 4; m++)                          \
            _Pragma("unroll") for (int n = 0; n < 4; n++)                      \
                acc[m][n] = __builtin_amdgcn_mfma_f32_16x16x32_bf16(           \
                    a[m], b[n], acc[m][n], 0, 0, 0);                           \
        __builtin_amdgcn_s_setprio(0);                                         \
    }
#define PHASE4(tt, SLOT)                                                       \
    if ((tt) < nt) {                                                           \
        if ((tt) + 3 < nt) STAGE4(((tt) + 3) & 3, ((tt) + 3) * 32);            \
        COMPUTE4(SLOT);                                                        \
        asm volatile("s_waitcnt lgkmcnt(0)" ::: "memory");                     \
        if ((tt) + 3 < nt) {                                                   \
            asm volatile("s_waitcnt vmcnt(8)" ::: "memory");                   \
        } else if ((tt) + 2 < nt) {                                            \
            asm volatile("s_waitcnt vmcnt(4)" ::: "memory");                   \
        } else if ((tt) + 1 < nt) {                                            \
            asm volatile("s_waitcnt vmcnt(0)" ::: "memory");                   \
        }                                                                      \
        __builtin_amdgcn_sched_barrier(0);                                     \
        __builtin_amdgcn_s_barrier();                                          \
        __builtin_amdgcn_sched_barrier(0);                                     \
    }

    int nt = K >> 5;   // 64 for fc2
    STAGE4(0, 0);
    STAGE4(1, 32);
    STAGE4(2, 64);
    asm volatile("s_waitcnt vmcnt(8)" ::: "memory");   // tile 0 landed
    __builtin_amdgcn_sched_barrier(0);
    __builtin_amdgcn_s_barrier();
    __builtin_amdgcn_sched_barrier(0);
#pragma unroll 1
    for (int t = 0; t < nt; t += 4) {
        PHASE4(t, 0);
        PHASE4(t + 1, 1);
        PHASE4(t + 2, 2);
        PHASE4(t + 3, 3);
    }
#undef STAGE4
#undef COMPUTE4
#undef PHASE4

    int gcolb = bn * 128 + wc * 64;
    int grb = bm * 128 + wr * 64;
#pragma unroll
    for (int m = 0; m < 4; m++)
#pragma unroll
        for (int n = 0; n < 4; n++) {
            int col = gcolb + n * 16 + fr;
            float bv = bias[col];
#pragma unroll
            for (int r = 0; r < 4; r++) {
                int row = grb + m * 16 + g * 4 + r;
                size_t o = (size_t)row * 512 + col;
                Cout[o] = acc[m][n][r] + bv + resid[o];
            }
        }
}

// Flash attention (R13-proven dataflow + deferred max/sum bookkeeping).
__global__ __launch_bounds__(256, 4) void k_attn(const u16* __restrict__ qb,
                                                 const u16* __restrict__ kb,
                                                 const u16* __restrict__ vtb,
                                                 u16* __restrict__ o) {
    __shared__ u16 K0[4096], K1[4096], V0[4096], V1[4096];  // [row 64][64]
    __shared__ u16 Ps[4096];                                 // [64][64] swizzled
    int bid = blockIdx.x;
    int wg = (bid & 7) * 512 + (bid >> 3);   // bijective XCD chunking (4096%8==0)
    int qc = wg & 7;
    int pair = wg >> 3;
    int hh = pair & 7, win = pair >> 3;
    int wave = threadIdx.x >> 6, lane = threadIdx.x & 63;
    const u16* kbw = kb + ((size_t)(win * 8 + hh)) * 512 * 64;
    const u16* vtw = vtb + ((size_t)(win * 8 + hh)) * 64 * 512;

    const u16* qrow = qb + ((size_t)hh * 512 + qc * 64 + (wave << 4) + (lane & 15)) * 64 + (lane >> 4) * 8;
    bfrag aq0 = *(const bfrag*)(qrow);
    bfrag aq1 = *(const bfrag*)(qrow + 32);

    ffrag acc[4] = {};
    float m_run[4], l_run[4];
#pragma unroll
    for (int r = 0; r < 4; r++) { m_run[r] = -1e30f; l_run[r] = 0.0f; }

    int srow = lane >> 3;                        // staging sub-row
    int sxo = ((lane & 7) ^ srow) * 8;           // pre-swizzled source chunk
    int fr = lane & 15;
    int fkc = lane >> 4;                         // logical k-chunk 0..3
    int kx0 = (fkc ^ (fr & 7)) * 8;              // physical chunk, k 0..31
    int kx1 = ((fkc + 4) ^ (fr & 7)) * 8;        // k 32..63
    int arow = (wave << 4) + fr;
    int pswz = (arow & 7) << 3;                  // Ps read swizzle (arow&7 == fr&7)

#define STAGE_KV(KS, VS, kc)                                                   \
    {                                                                          \
        GLOAD16(kbw + (size_t)((kc) * 64 + wave * 8 + srow) * 64 + sxo,        \
                KS + wave * 512);                                              \
        GLOAD16(kbw + (size_t)((kc) * 64 + 32 + wave * 8 + srow) * 64 + sxo,   \
                KS + 2048 + wave * 512);                                       \
        GLOAD16(vtw + (size_t)(wave * 8 + srow) * 512 + (kc) * 64 + sxo,       \
                VS + wave * 512);                                              \
        GLOAD16(vtw + (size_t)(32 + wave * 8 + srow) * 512 + (kc) * 64 + sxo,  \
                VS + 2048 + wave * 512);                                       \
    }
#define ATT_COMPUTE(KS, VS)                                                    \
    {                                                                          \
        ffrag s[4] = {};                                                       \
        _Pragma("unroll") for (int j = 0; j < 4; j++) {                        \
            bfrag b0 = *(const bfrag*)(KS + (j * 16 + fr) * 64 + kx0);         \
            s[j] = __builtin_amdgcn_mfma_f32_16x16x32_bf16(aq0, b0, s[j], 0, 0, 0); \
            bfrag b1 = *(const bfrag*)(KS + (j * 16 + fr) * 64 + kx1);         \
            s[j] = __builtin_amdgcn_mfma_f32_16x16x32_bf16(aq1, b1, s[j], 0, 0, 0); \
        }                                                                      \
        int need = 0;                                                          \
        _Pragma("unroll") for (int r = 0; r < 4; r++) {                        \
            float mxj = fmaxf(fmaxf(s[0][r], s[1][r]),                         \
                              fmaxf(s[2][r], s[3][r]));                        \
            need |= (mxj > m_run[r] + 8.0f) ? 1 : 0;                           \
        }                                                                      \
        if (__any(need)) {                                                     \
            _Pragma("unroll") for (int r = 0; r < 4; r++) {                    \
                float mx = fmaxf(fmaxf(s[0][r], s[1][r]),                      \
                                 fmaxf(s[2][r], s[3][r]));                     \
                _Pragma("unroll") for (int d = 1; d < 16; d <<= 1)             \
                    mx = fmaxf(mx, __shfl_xor(mx, d));                         \
                float mnew = fmaxf(m_run[r], mx);                              \
                float alpha = __expf(m_run[r] - mnew);                         \
                m_run[r] = mnew;                                               \
                l_run[r] *= alpha;                                             \
                _Pragma("unroll") for (int j = 0; j < 4; j++)                  \
                    acc[j][r] *= alpha;                                        \
            }                                                                  \
        }                                                                      \
        _Pragma("unroll") for (int j = 0; j < 4; j++)                          \
            _Pragma("unroll") for (int r = 0; r < 4; r++) {                    \
                float p = __expf(s[j][r] - m_run[r]);                          \
                l_run[r] += p;                                                 \
                int prow = (wave << 4) + (lane >> 4) * 4 + r;                  \
                Ps[prow * 64 + ((j * 16 + fr) ^ ((prow & 7) << 3))] = f2bf(p); \
            }                                                                  \
        bfrag ap0 = *(const bfrag*)(&Ps[arow * 64 + ((fkc * 8) ^ pswz)]);      \
        bfrag ap1 = *(const bfrag*)(&Ps[arow * 64 + ((32 + fkc * 8) ^ pswz)]); \
        _Pragma("unroll") for (int j = 0; j < 4; j++) {                        \
            bfrag v0 = *(const bfrag*)(VS + (j * 16 + fr) * 64 + kx0);         \
            acc[j] = __builtin_amdgcn_mfma_f32_16x16x32_bf16(ap0, v0, acc[j], 0, 0, 0); \
            bfrag v1 = *(const bfrag*)(VS + (j * 16 + fr) * 64 + kx1);         \
            acc[j] = __builtin_amdgcn_mfma_f32_16x16x32_bf16(ap1, v1, acc[j], 0, 0, 0); \
        }                                                                      \
    }

    STAGE_KV(K0, V0, 0);
    __syncthreads();
#pragma unroll 1
    for (int kc = 0; kc < 8; kc += 2) {
        if (kc + 1 < 8) STAGE_KV(K1, V1, kc + 1);
        ATT_COMPUTE(K0, V0);
        __syncthreads();
        if (kc + 2 < 8) STAGE_KV(K0, V0, kc + 2);
        ATT_COMPUTE(K1, V1);
        __syncthreads();
    }
#undef STAGE_KV
#undef ATT_COMPUTE

    // deferred sum-reduce: lane partials -> full row sums (once)
#pragma unroll
    for (int r = 0; r < 4; r++) {
#pragma unroll
        for (int d = 1; d < 16; d <<= 1)
            l_run[r] += __shfl_xor(l_run[r], d);
    }

    int row0 = qc * 64 + (wave << 4) + (lane >> 4) * 4;
#pragma unroll
    for (int j = 0; j < 4; j++) {
        int col = hh * 64 + j * 16 + fr;
#pragma unroll
        for (int r = 0; r < 4; r++) {
            float val = acc[j][r] / l_run[r];
            o[((size_t)win * 512 + row0 + r) * 512 + col] = f2bf(val);
        }
    }
}

extern "C" void kernel_launch(void* const* d_in, const int* in_sizes, int n_in,
                              void* d_out, int out_size, void* d_ws, size_t ws_size,
                              hipStream_t stream) {
    const float* x      = (const float*)d_in[0];
    const float* q_ms   = (const float*)d_in[1];
    const float* n1w    = (const float*)d_in[2];
    const float* n1b    = (const float*)d_in[3];
    const float* kv_w   = (const float*)d_in[4];
    const float* kv_b   = (const float*)d_in[5];
    const float* proj_w = (const float*)d_in[6];
    const float* proj_b = (const float*)d_in[7];
    const float* n2w    = (const float*)d_in[8];
    const float* n2b    = (const float*)d_in[9];
    const float* fc1_w  = (const float*)d_in[10];
    const float* fc1_b  = (const float*)d_in[11];
    const float* fc2_w  = (const float*)d_in[12];
    const float* fc2_b  = (const float*)d_in[13];

    char* ws = (char*)d_ws;
    const size_t OFF_XNW = 0;           // bf16 [32768][512]   33,554,432 B
    const size_t OFF_KB  = 33554432;    // bf16 [64][8][512][64]  33,554,432 B
    const size_t OFF_VT  = 67108864;    // bf16 [64][8][64][512]  33,554,432 B
    const size_t OFF_O   = 100663296;   // bf16 [32768][512]   33,554,432 B
    const size_t OFF_HID = 0;           // bf16 [32768][2048] (aliases dead bufs)
    const size_t OFF_X1  = 134217728;   // f32  [32768][512]   67,108,864 B
    const size_t OFF_XN2 = 201326592;   // bf16 [32768][512]   33,554,432 B
    const size_t OFF_W   = 234881024;   // transposed weights + q
    u16* xnw = (u16*)(ws + OFF_XNW);
    u16* kbb = (u16*)(ws + OFF_KB);
    u16* vtb = (u16*)(ws + OFF_VT);
    u16* ob  = (u16*)(ws + OFF_O);
    u16* hid = (u16*)(ws + OFF_HID);
    float* x1 = (float*)(ws + OFF_X1);
    u16* xn2 = (u16*)(ws + OFF_XN2);
    u16* kv_wt   = (u16*)(ws + OFF_W);        // [1024][512]
    u16* proj_wt = kv_wt + 512 * 1024;        // [512][512]
    u16* fc1_wt  = proj_wt + 512 * 512;       // [2048][512]
    u16* fc2_wt  = fc1_wt + 512 * 2048;       // [512][2048]
    u16* qbf     = fc2_wt + 2048 * 512;       // [8][512][64]
    size_t need = OFF_W + (size_t)(512 * 1024 + 512 * 512 + 512 * 2048 + 2048 * 512 + 8 * 512 * 64) * 2;
    if (ws_size < need) return;

    k_ln<<<8192, 256, 0, stream>>>(x, n1w, n1b, xnw, 1);
    k_prep<<<12288, 256, 0, stream>>>(kv_w, proj_w, fc1_w, fc2_w, q_ms,
                                      kv_wt, proj_wt, fc1_wt, fc2_wt, qbf);

    k_gemm128<0><<<2048, 256, 0, stream>>>(xnw, kv_wt, kv_b, kbb, 512, 1024, nullptr, vtb);
    k_attn<<<dim3(4096), 256, 0, stream>>>(qbf, kbb, vtb, ob);
    k_gemm128<1><<<1024, 256, 0, stream>>>(ob, proj_wt, proj_b, x1, 512, 512, x, nullptr);
    k_ln<<<8192, 256, 0, stream>>>(x1, n2w, n2b, xn2, 0);
    k_gemm128<2><<<4096, 256, 0, stream>>>(xn2, fc1_wt, fc1_b, hid, 512, 2048, nullptr, nullptr);
    k_gemm128d4<<<1024, 256, 0, stream>>>(hid, fc2_wt, fc2_b, (float*)d_out, 2048, 512, x1);
}

// Round 18
// 413.743 us; speedup vs baseline: 1.8923x; 1.0026x over previous
//
#include <hip/hip_runtime.h>

typedef unsigned short u16;
typedef __attribute__((ext_vector_type(8))) short bfrag;   // 8 x bf16
typedef __attribute__((ext_vector_type(4))) float ffrag;   // 4 x f32

#define LN_EPS 1e-5f

#define GLOAD16(g, l)                                                          \
    __builtin_amdgcn_global_load_lds(                                          \
        (const __attribute__((address_space(1))) void*)(g),                    \
        (__attribute__((address_space(3))) void*)(l), 16, 0, 0)

__device__ __forceinline__ u16 f2bf(float f) {
    unsigned u = __builtin_bit_cast(unsigned, f);
    u += 0x7fffu + ((u >> 16) & 1u);   // RNE
    return (u16)(u >> 16);
}

// windowed token index -> image row index
__device__ __forceinline__ int win_to_img(int tok) {
    int win = tok >> 9, n = tok & 511;
    int wh = win >> 4, ww = (win >> 2) & 3, wd = win & 3;
    int ph = n >> 6, pw = (n >> 3) & 7, pd = n & 7;
    return ((wh * 8 + ph) * 32 + (ww * 8 + pw)) * 32 + (wd * 8 + pd);
}

// LayerNorm over C=512, one wave per token.
__global__ __launch_bounds__(256) void k_ln(const float* __restrict__ x,
                                            const float* __restrict__ w,
                                            const float* __restrict__ b,
                                            u16* __restrict__ out, int windowed) {
    int wave = threadIdx.x >> 6, lane = threadIdx.x & 63;
    int tok = blockIdx.x * 4 + wave;
    int src = windowed ? win_to_img(tok) : tok;
    const float* xr = x + (size_t)src * 512;
    float v[8];
#pragma unroll
    for (int i = 0; i < 2; i++) {
        float4 f = *(const float4*)(xr + i * 256 + lane * 4);
        v[i * 4 + 0] = f.x; v[i * 4 + 1] = f.y; v[i * 4 + 2] = f.z; v[i * 4 + 3] = f.w;
    }
    float s = 0.f;
#pragma unroll
    for (int i = 0; i < 8; i++) s += v[i];
#pragma unroll
    for (int m = 1; m < 64; m <<= 1) s += __shfl_xor(s, m);
    float mean = s * (1.0f / 512.0f);
    float vs = 0.f;
#pragma unroll
    for (int i = 0; i < 8; i++) { float d = v[i] - mean; vs += d * d; }
#pragma unroll
    for (int m = 1; m < 64; m <<= 1) vs += __shfl_xor(vs, m);
    float rstd = rsqrtf(vs * (1.0f / 512.0f) + LN_EPS);
    u16* orow = out + (size_t)tok * 512;
#pragma unroll
    for (int i = 0; i < 2; i++) {
        int c0 = i * 256 + lane * 4;
        ushort4 o;
        o.x = f2bf((v[i * 4 + 0] - mean) * rstd * w[c0 + 0] + b[c0 + 0]);
        o.y = f2bf((v[i * 4 + 1] - mean) * rstd * w[c0 + 1] + b[c0 + 1]);
        o.z = f2bf((v[i * 4 + 2] - mean) * rstd * w[c0 + 2] + b[c0 + 2]);
        o.w = f2bf((v[i * 4 + 3] - mean) * rstd * w[c0 + 3] + b[c0 + 3]);
        *(ushort4*)(orow + c0) = o;
    }
}

// Merged prep: 4 weight transposes (f32 [K][N] -> bf16 [N][K]) + q scale/cast.
__global__ __launch_bounds__(256) void k_prep(const float* __restrict__ kv_w,
                                              const float* __restrict__ proj_w,
                                              const float* __restrict__ fc1_w,
                                              const float* __restrict__ fc2_w,
                                              const float* __restrict__ q,
                                              u16* __restrict__ kv_wt,
                                              u16* __restrict__ proj_wt,
                                              u16* __restrict__ fc1_wt,
                                              u16* __restrict__ fc2_wt,
                                              u16* __restrict__ qbf) {
    int i = blockIdx.x * 256 + threadIdx.x;
    if (i < 524288) {                       // kv_wt [1024][512]
        int n = i >> 9, k = i & 511;
        kv_wt[i] = f2bf(kv_w[k * 1024 + n]);
    } else if (i < 786432) {                // proj_wt [512][512]
        int j = i - 524288, n = j >> 9, k = j & 511;
        proj_wt[j] = f2bf(proj_w[k * 512 + n]);
    } else if (i < 1835008) {               // fc1_wt [2048][512]
        int j = i - 786432, n = j >> 9, k = j & 511;
        fc1_wt[j] = f2bf(fc1_w[k * 2048 + n]);
    } else if (i < 2883584) {               // fc2_wt [512][2048]
        int j = i - 1835008, n = j >> 11, k = j & 2047;
        fc2_wt[j] = f2bf(fc2_w[k * 512 + n]);
    } else {                                // qbf [8*512*64], pre-scaled
        int j = i - 2883584;
        qbf[j] = f2bf(q[j] * 0.125f);
    }
}

// ==== 128x128 GEMM, BK=32, 4 waves (2x2), 2-phase dbuf — kv/proj only ====
// EPI 0: +bias -> K [win][h][key][d] / V^T [win][h][d][key]
// EPI 1: +bias, scatter windowed->image, + resid(x) -> f32
template <int EPI>
__global__ __launch_bounds__(256, 4) void k_gemm128(const u16* __restrict__ A,
                                                    const u16* __restrict__ Bt,
                                                    const float* __restrict__ bias,
                                                    void* __restrict__ Cout, int K, int Nn,
                                                    const float* __restrict__ resid,
                                                    void* __restrict__ Cout2) {
    __shared__ u16 As0[4096], Bs0[4096], As1[4096], Bs1[4096];
    int tid = threadIdx.x;
    int wave = tid >> 6, lane = tid & 63;
    int wr = wave >> 1, wc = wave & 1;

    int gx = Nn >> 7;
    int nwg = gridDim.x;
    int wg = blockIdx.x;
    int wgs = (wg & 7) * (nwg >> 3) + (wg >> 3);   // XCD chunking (nwg%8==0)
    int bn = wgs % gx, bm = wgs / gx;

    int rt = wave * 32 + (lane >> 2);
    int sxo = ((lane & 3) ^ ((rt ^ (rt >> 2)) & 3)) * 8;
    const u16* Ag = A + (size_t)(bm * 128 + rt) * K + sxo;
    const u16* Bg = Bt + (size_t)(bn * 128 + rt) * K + sxo;

    int fr = lane & 15, g = lane >> 4;
    int pco = (g ^ ((fr ^ (fr >> 2)) & 3)) * 8;

    ffrag acc[4][4] = {};

#define STAGE(AS, BS, k0)                                                      \
    {                                                                          \
        GLOAD16(Ag + (k0), AS + wave * 1024);                                  \
        GLOAD16(Ag + (k0) + 16 * K, AS + wave * 1024 + 512);                   \
        GLOAD16(Bg + (k0), BS + wave * 1024);                                  \
        GLOAD16(Bg + (k0) + 16 * K, BS + wave * 1024 + 512);                   \
    }
#define COMPUTE(AS, BS)                                                        \
    {                                                                          \
        bfrag a[4], b[4];                                                      \
        _Pragma("unroll") for (int m = 0; m < 4; m++)                          \
            a[m] = *(const bfrag*)(AS + (wr * 64 + m * 16 + fr) * 32 + pco);   \
        _Pragma("unroll") for (int n = 0; n < 4; n++)                          \
            b[n] = *(const bfrag*)(BS + (wc * 64 + n * 16 + fr) * 32 + pco);   \
        _Pragma("unroll") for (int m = 0; m < 4; m++)                          \
            _Pragma("unroll") for (int n = 0; n < 4; n++)                      \
                acc[m][n] = __builtin_amdgcn_mfma_f32_16x16x32_bf16(           \
                    a[m], b[n], acc[m][n], 0, 0, 0);                           \
    }

    int nt = K >> 5;
    STAGE(As0, Bs0, 0);
    __syncthreads();
    int t = 0;
    for (; t + 2 < nt; t += 2) {
        STAGE(As1, Bs1, (t + 1) * 32);
        COMPUTE(As0, Bs0);
        __syncthreads();
        STAGE(As0, Bs0, (t + 2) * 32);
        COMPUTE(As1, Bs1);
        __syncthreads();
    }
    STAGE(As1, Bs1, (nt - 1) * 32);
    COMPUTE(As0, Bs0);
    __syncthreads();
    COMPUTE(As1, Bs1);
#undef STAGE
#undef COMPUTE

    int gcolb = bn * 128 + wc * 64;
    int grb = bm * 128 + wr * 64;

    if constexpr (EPI == 0) {
        __syncthreads();
        u16* ep = (wave == 0) ? As0 : (wave == 1) ? Bs0 : (wave == 2) ? As1 : Bs1;
        int h = (gcolb >> 6) & 7;
        bool isK = (gcolb < 512);
#pragma unroll
        for (int m = 0; m < 4; m++)
#pragma unroll
            for (int n = 0; n < 4; n++) {
                float bv = bias[gcolb + n * 16 + fr];
#pragma unroll
                for (int r = 0; r < 4; r++) {
                    int wq = m * 16 + g * 4 + r;
                    int wcc = n * 16 + fr;
                    float val = acc[m][n][r] + bv;
                    if (isK)
                        ep[wq * 64 + (wcc ^ ((wq & 7) << 3))] = f2bf(val);
                    else
                        ep[wcc * 64 + (wq ^ ((wcc & 7) << 3))] = f2bf(val);
                }
            }
#pragma unroll
        for (int rd = 0; rd < 8; rd++) {
            int row = rd * 8 + (lane >> 3);
            int ch = (lane & 7) ^ (row & 7);
            int4 v = *(const int4*)(ep + row * 64 + ch * 8);
            if (isK) {
                int tok = grb + row;
                int win = tok >> 9, key = tok & 511;
                *(int4*)(&((u16*)Cout)[(((size_t)(win * 8 + h)) * 512 + key) * 64 + (lane & 7) * 8]) = v;
            } else {
                int win = grb >> 9, key0 = grb & 511;
                *(int4*)(&((u16*)Cout2)[(((size_t)(win * 8 + h)) * 64 + row) * 512 + key0 + (lane & 7) * 8]) = v;
            }
        }
    } else {
#pragma unroll
        for (int m = 0; m < 4; m++)
#pragma unroll
            for (int n = 0; n < 4; n++) {
                int col = gcolb + n * 16 + fr;
                float bv = bias[col];
#pragma unroll
                for (int r = 0; r < 4; r++) {
                    int row = grb + m * 16 + g * 4 + r;
                    float val = acc[m][n][r] + bv;
                    int ri = win_to_img(row);
                    size_t o = (size_t)ri * 512 + col;
                    ((float*)Cout)[o] = val + resid[o];
                }
            }
    }
}

// ==== 256x256 phased GEMM, BK=64, 8 waves (2Mx4N), wave tile 128x64 ====
// 2 LDS buffers (128KB, 1 block/CU). Per K-tile: issue ALL 8 gloads for tile
// t+1 first (wait is a full tile of compute later), read 8 B-frags once, then
// 4 quadrant-phases {4 a-reads -> setprio -> 16 MFMA -> setprio}. One fence
// stack per tile: lgkmcnt(0) [buffer reads retired before others overwrite;
// rule #18] -> vmcnt(0) [tile t+1 landed, issued ~4 phases ago] ->
// sched_barrier | s_barrier | sched_barrier (R10-proven).
// Swizzle: LDS[r][c] = global[r][c ^ f(r)], f(r) = (r ^ (r>>2)) & 7; read side
// per-frag: f = fr ^ (fr>>2) ^ ((idx&1)<<2) (derived: rows = base16*idx + fr).
// EPI 2: +bias, tanh-GELU -> bf16, LDS-restaged coalesced stores (fc1)
// EPI 3: +bias, + resid -> f32 direct (fc2)
template <int EPI>
__global__ __launch_bounds__(512, 2) void k_gemm256p(const u16* __restrict__ A,
                                                     const u16* __restrict__ Bt,
                                                     const float* __restrict__ bias,
                                                     void* __restrict__ Cout, int K, int Nn,
                                                     const float* __restrict__ resid) {
    __shared__ u16 sm[65536];   // 2 bufs x (A [256][64] @0 | B [256][64] @16384)
    int tid = threadIdx.x;
    int wave = tid >> 6, lane = tid & 63;
    int wm = wave >> 2, wn = wave & 3;

    int gx = Nn >> 8;
    int nwg = gridDim.x;
    int wg = blockIdx.x;
    int wgs = (wg & 7) * (nwg >> 3) + (wg >> 3);   // XCD chunking (nwg%8==0)
    int bn = wgs % gx, bm = wgs / gx;

    // staging: lane l of wave w -> row i*64 + w*8 + (l>>3), dest chunk l&7.
    // sr = tid>>3 = w*8 + (l>>3); f(i*64+sr) = f(sr) (i*64 drops out of &7 bits)
    int sr = tid >> 3;
    int sf = (sr ^ (sr >> 2)) & 7;
    int sxo = ((tid & 7) ^ sf) * 8;
    const u16* Ag = A + (size_t)(bm * 256 + sr) * K + sxo;
    const u16* Bg = Bt + (size_t)(bn * 256 + sr) * K + sxo;
    size_t rowK = (size_t)64 * K;

    int fr = lane & 15, g = lane >> 4;
    int fb0 = (fr ^ (fr >> 2)) & 7;

    ffrag acc[8][4] = {};

#define STAGE256(SLOT, k0)                                                     \
    {                                                                          \
        u16* d = sm + (SLOT) * 32768 + wave * 512;                             \
        _Pragma("unroll") for (int i = 0; i < 4; i++)                          \
            GLOAD16(Ag + (k0) + i * rowK, d + i * 4096);                       \
        _Pragma("unroll") for (int i = 0; i < 4; i++)                          \
            GLOAD16(Bg + (k0) + i * rowK, d + 16384 + i * 4096);               \
    }

    int nt = K >> 6;
    STAGE256(0, 0);
    asm volatile("s_waitcnt vmcnt(0)" ::: "memory");
    __builtin_amdgcn_sched_barrier(0);
    __builtin_amdgcn_s_barrier();
    __builtin_amdgcn_sched_barrier(0);

#pragma unroll 1
    for (int t = 0; t < nt; ++t) {
        const u16* Ab = sm + (t & 1) * 32768;
        const u16* Bb = Ab + 16384;
        if (t + 1 < nt) STAGE256((t + 1) & 1, (size_t)(t + 1) * 64);
        bfrag bfr[8];
#pragma unroll
        for (int n = 0; n < 4; n++)
#pragma unroll
            for (int s = 0; s < 2; s++)
                bfr[n * 2 + s] = *(const bfrag*)(Bb + (wn * 64 + n * 16 + fr) * 64 +
                                  (((g + 4 * s) ^ fb0 ^ ((n & 1) << 2)) & 7) * 8);
#pragma unroll
        for (int q = 0; q < 4; q++) {
            bfrag afr[4];
#pragma unroll
            for (int mm = 0; mm < 2; mm++)
#pragma unroll
                for (int s = 0; s < 2; s++) {
                    int m = q * 2 + mm;
                    afr[mm * 2 + s] = *(const bfrag*)(Ab + (wm * 128 + m * 16 + fr) * 64 +
                                      (((g + 4 * s) ^ fb0 ^ ((m & 1) << 2)) & 7) * 8);
                }
            __builtin_amdgcn_s_setprio(1);
#pragma unroll
            for (int mm = 0; mm < 2; mm++)
#pragma unroll
                for (int n = 0; n < 4; n++)
#pragma unroll
                    for (int s = 0; s < 2; s++)
                        acc[q * 2 + mm][n] = __builtin_amdgcn_mfma_f32_16x16x32_bf16(
                            afr[mm * 2 + s], bfr[n * 2 + s], acc[q * 2 + mm][n], 0, 0, 0);
            __builtin_amdgcn_s_setprio(0);
        }
        asm volatile("s_waitcnt lgkmcnt(0)" ::: "memory");
        asm volatile("s_waitcnt vmcnt(0)" ::: "memory");
        __builtin_amdgcn_sched_barrier(0);
        __builtin_amdgcn_s_barrier();
        __builtin_amdgcn_sched_barrier(0);
    }
#undef STAGE256

    int gcb = bn * 256 + wn * 64;     // wave col base
    int grb = bm * 256 + wm * 128;    // wave row base

    if constexpr (EPI == 2) {
        // wave-private 16KB restage (8 waves x 8192 u16 = whole sm; all waves
        // are past the final barrier with LDS reads lgkm-drained)
        u16* ep = sm + wave * 8192;
#pragma unroll
        for (int m = 0; m < 8; m++)
#pragma unroll
            for (int n = 0; n < 4; n++) {
                float bv = bias[gcb + n * 16 + fr];
#pragma unroll
                for (int r = 0; r < 4; r++) {
                    int rl = m * 16 + g * 4 + r;
                    int cl = n * 16 + fr;
                    float xx = acc[m][n][r] + bv;
                    float inner = fmaf(0.044715f * xx * xx, xx, xx);
                    float e = __expf(-1.5957691216f * inner);
                    float val = xx * __builtin_amdgcn_rcpf(1.0f + e);
                    ep[rl * 64 + (cl ^ ((rl & 7) << 3))] = f2bf(val);
                }
            }
#pragma unroll
        for (int it = 0; it < 16; it++) {
            int rl = it * 8 + (lane >> 3);
            int ch = (lane & 7) ^ (rl & 7);
            int4 v = *(const int4*)(ep + rl * 64 + ch * 8);
            *(int4*)(&((u16*)Cout)[(size_t)(grb + rl) * Nn + gcb + (lane & 7) * 8]) = v;
        }
    } else {
#pragma unroll
        for (int m = 0; m < 8; m++)
#pragma unroll
            for (int n = 0; n < 4; n++) {
                int col = gcb + n * 16 + fr;
                float bv = bias[col];
#pragma unroll
                for (int r = 0; r < 4; r++) {
                    int row = grb + m * 16 + g * 4 + r;
                    size_t o = (size_t)row * 512 + col;
                    ((float*)Cout)[o] = acc[m][n][r] + bv + resid[o];
                }
            }
    }
}

// Flash attention (R13-proven dataflow + deferred max/sum bookkeeping).
__global__ __launch_bounds__(256, 4) void k_attn(const u16* __restrict__ qb,
                                                 const u16* __restrict__ kb,
                                                 const u16* __restrict__ vtb,
                                                 u16* __restrict__ o) {
    __shared__ u16 K0[4096], K1[4096], V0[4096], V1[4096];  // [row 64][64]
    __shared__ u16 Ps[4096];                                 // [64][64] swizzled
    int bid = blockIdx.x;
    int wg = (bid & 7) * 512 + (bid >> 3);   // bijective XCD chunking (4096%8==0)
    int qc = wg & 7;
    int pair = wg >> 3;
    int hh = pair & 7, win = pair >> 3;
    int wave = threadIdx.x >> 6, lane = threadIdx.x & 63;
    const u16* kbw = kb + ((size_t)(win * 8 + hh)) * 512 * 64;
    const u16* vtw = vtb + ((size_t)(win * 8 + hh)) * 64 * 512;

    const u16* qrow = qb + ((size_t)hh * 512 + qc * 64 + (wave << 4) + (lane & 15)) * 64 + (lane >> 4) * 8;
    bfrag aq0 = *(const bfrag*)(qrow);
    bfrag aq1 = *(const bfrag*)(qrow + 32);

    ffrag acc[4] = {};
    float m_run[4], l_run[4];
#pragma unroll
    for (int r = 0; r < 4; r++) { m_run[r] = -1e30f; l_run[r] = 0.0f; }

    int srow = lane >> 3;
    int sxo = ((lane & 7) ^ srow) * 8;
    int fr = lane & 15;
    int fkc = lane >> 4;
    int kx0 = (fkc ^ (fr & 7)) * 8;
    int kx1 = ((fkc + 4) ^ (fr & 7)) * 8;
    int arow = (wave << 4) + fr;
    int pswz = (arow & 7) << 3;

#define STAGE_KV(KS, VS, kc)                                                   \
    {                                                                          \
        GLOAD16(kbw + (size_t)((kc) * 64 + wave * 8 + srow) * 64 + sxo,        \
                KS + wave * 512);                                              \
        GLOAD16(kbw + (size_t)((kc) * 64 + 32 + wave * 8 + srow) * 64 + sxo,   \
                KS + 2048 + wave * 512);                                       \
        GLOAD16(vtw + (size_t)(wave * 8 + srow) * 512 + (kc) * 64 + sxo,       \
                VS + wave * 512);                                              \
        GLOAD16(vtw + (size_t)(32 + wave * 8 + srow) * 512 + (kc) * 64 + sxo,  \
                VS + 2048 + wave * 512);                                       \
    }
#define ATT_COMPUTE(KS, VS)                                                    \
    {                                                                          \
        ffrag s[4] = {};                                                       \
        _Pragma("unroll") for (int j = 0; j < 4; j++) {                        \
            bfrag b0 = *(const bfrag*)(KS + (j * 16 + fr) * 64 + kx0);         \
            s[j] = __builtin_amdgcn_mfma_f32_16x16x32_bf16(aq0, b0, s[j], 0, 0, 0); \
            bfrag b1 = *(const bfrag*)(KS + (j * 16 + fr) * 64 + kx1);         \
            s[j] = __builtin_amdgcn_mfma_f32_16x16x32_bf16(aq1, b1, s[j], 0, 0, 0); \
        }                                                                      \
        int need = 0;                                                          \
        _Pragma("unroll") for (int r = 0; r < 4; r++) {                        \
            float mxj = fmaxf(fmaxf(s[0][r], s[1][r]),                         \
                              fmaxf(s[2][r], s[3][r]));                        \
            need |= (mxj > m_run[r] + 8.0f) ? 1 : 0;                           \
        }                                                                      \
        if (__any(need)) {                                                     \
            _Pragma("unroll") for (int r = 0; r < 4; r++) {                    \
                float mx = fmaxf(fmaxf(s[0][r], s[1][r]),                      \
                                 fmaxf(s[2][r], s[3][r]));                     \
                _Pragma("unroll") for (int d = 1; d < 16; d <<= 1)             \
                    mx = fmaxf(mx, __shfl_xor(mx, d));                         \
                float mnew = fmaxf(m_run[r], mx);                              \
                float alpha = __expf(m_run[r] - mnew);                         \
                m_run[r] = mnew;                                               \
                l_run[r] *= alpha;                                             \
                _Pragma("unroll") for (int j = 0; j < 4; j++)                  \
                    acc[j][r] *= alpha;                                        \
            }                                                                  \
        }                                                                      \
        _Pragma("unroll") for (int j = 0; j < 4; j++)                          \
            _Pragma("unroll") for (int r = 0; r < 4; r++) {                    \
                float p = __expf(s[j][r] - m_run[r]);                          \
                l_run[r] += p;                                                 \
                int prow = (wave << 4) + (lane >> 4) * 4 + r;                  \
                Ps[prow * 64 + ((j * 16 + fr) ^ ((prow & 7) << 3))] = f2bf(p); \
            }                                                                  \
        bfrag ap0 = *(const bfrag*)(&Ps[arow * 64 + ((fkc * 8) ^ pswz)]);      \
        bfrag ap1 = *(const bfrag*)(&Ps[arow * 64 + ((32 + fkc * 8) ^ pswz)]); \
        _Pragma("unroll") for (int j = 0; j < 4; j++) {                        \
            bfrag v0 = *(const bfrag*)(VS + (j * 16 + fr) * 64 + kx0);         \
            acc[j] = __builtin_amdgcn_mfma_f32_16x16x32_bf16(ap0, v0, acc[j], 0, 0, 0); \
            bfrag v1 = *(const bfrag*)(VS + (j * 16 + fr) * 64 + kx1);         \
            acc[j] = __builtin_amdgcn_mfma_f32_16x16x32_bf16(ap1, v1, acc[j], 0, 0, 0); \
        }                                                                      \
    }

    STAGE_KV(K0, V0, 0);
    __syncthreads();
#pragma unroll 1
    for (int kc = 0; kc < 8; kc += 2) {
        if (kc + 1 < 8) STAGE_KV(K1, V1, kc + 1);
        ATT_COMPUTE(K0, V0);
        __syncthreads();
        if (kc + 2 < 8) STAGE_KV(K0, V0, kc + 2);
        ATT_COMPUTE(K1, V1);
        __syncthreads();
    }
#undef STAGE_KV
#undef ATT_COMPUTE

#pragma unroll
    for (int r = 0; r < 4; r++) {
#pragma unroll
        for (int d = 1; d < 16; d <<= 1)
            l_run[r] += __shfl_xor(l_run[r], d);
    }

    int row0 = qc * 64 + (wave << 4) + (lane >> 4) * 4;
#pragma unroll
    for (int j = 0; j < 4; j++) {
        int col = hh * 64 + j * 16 + fr;
#pragma unroll
        for (int r = 0; r < 4; r++) {
            float val = acc[j][r] / l_run[r];
            o[((size_t)win * 512 + row0 + r) * 512 + col] = f2bf(val);
        }
    }
}

extern "C" void kernel_launch(void* const* d_in, const int* in_sizes, int n_in,
                              void* d_out, int out_size, void* d_ws, size_t ws_size,
                              hipStream_t stream) {
    const float* x      = (const float*)d_in[0];
    const float* q_ms   = (const float*)d_in[1];
    const float* n1w    = (const float*)d_in[2];
    const float* n1b    = (const float*)d_in[3];
    const float* kv_w   = (const float*)d_in[4];
    const float* kv_b   = (const float*)d_in[5];
    const float* proj_w = (const float*)d_in[6];
    const float* proj_b = (const float*)d_in[7];
    const float* n2w    = (const float*)d_in[8];
    const float* n2b    = (const float*)d_in[9];
    const float* fc1_w  = (const float*)d_in[10];
    const float* fc1_b  = (const float*)d_in[11];
    const float* fc2_w  = (const float*)d_in[12];
    const float* fc2_b  = (const float*)d_in[13];

    char* ws = (char*)d_ws;
    const size_t OFF_XNW = 0;           // bf16 [32768][512]   33,554,432 B
    const size_t OFF_KB  = 33554432;    // bf16 [64][8][512][64]  33,554,432 B
    const size_t OFF_VT  = 67108864;    // bf16 [64][8][64][512]  33,554,432 B
    const size_t OFF_O   = 100663296;   // bf16 [32768][512]   33,554,432 B
    const size_t OFF_HID = 0;           // bf16 [32768][2048] (aliases dead bufs)
    const size_t OFF_X1  = 134217728;   // f32  [32768][512]   67,108,864 B
    const size_t OFF_XN2 = 201326592;   // bf16 [32768][512]   33,554,432 B
    const size_t OFF_W   = 234881024;   // transposed weights + q
    u16* xnw = (u16*)(ws + OFF_XNW);
    u16* kbb = (u16*)(ws + OFF_KB);
    u16* vtb = (u16*)(ws + OFF_VT);
    u16* ob  = (u16*)(ws + OFF_O);
    u16* hid = (u16*)(ws + OFF_HID);
    float* x1 = (float*)(ws + OFF_X1);
    u16* xn2 = (u16*)(ws + OFF_XN2);
    u16* kv_wt   = (u16*)(ws + OFF_W);        // [1024][512]
    u16* proj_wt = kv_wt + 512 * 1024;        // [512][512]
    u16* fc1_wt  = proj_wt + 512 * 512;       // [2048][512]
    u16* fc2_wt  = fc1_wt + 512 * 2048;       // [512][2048]
    u16* qbf     = fc2_wt + 2048 * 512;       // [8][512][64]
    size_t need = OFF_W + (size_t)(512 * 1024 + 512 * 512 + 512 * 2048 + 2048 * 512 + 8 * 512 * 64) * 2;
    if (ws_size < need) return;

    k_ln<<<8192, 256, 0, stream>>>(x, n1w, n1b, xnw, 1);
    k_prep<<<12288, 256, 0, stream>>>(kv_w, proj_w, fc1_w, fc2_w, q_ms,
                                      kv_wt, proj_wt, fc1_wt, fc2_wt, qbf);

    k_gemm128<0><<<2048, 256, 0, stream>>>(xnw, kv_wt, kv_b, kbb, 512, 1024, nullptr, vtb);
    k_attn<<<dim3(4096), 256, 0, stream>>>(qbf, kbb, vtb, ob);
    k_gemm128<1><<<1024, 256, 0, stream>>>(ob, proj_wt, proj_b, x1, 512, 512, x, nullptr);
    k_ln<<<8192, 256, 0, stream>>>(x1, n2w, n2b, xn2, 0);
    k_gemm256p<2><<<1024, 512, 0, stream>>>(xn2, fc1_wt, fc1_b, hid, 512, 2048, nullptr);
    k_gemm256p<3><<<256, 512, 0, stream>>>(hid, fc2_wt, fc2_b, d_out, 2048, 512, x1);
}

// Round 19
// 372.384 us; speedup vs baseline: 2.1025x; 1.1111x over previous
//
#include <hip/hip_runtime.h>

typedef unsigned short u16;
typedef __attribute__((ext_vector_type(8))) short bfrag;   // 8 x bf16
typedef __attribute__((ext_vector_type(4))) float ffrag;   // 4 x f32

#define LN_EPS 1e-5f

#define GLOAD16(g, l)                                                          \
    __builtin_amdgcn_global_load_lds(                                          \
        (const __attribute__((address_space(1))) void*)(g),                    \
        (__attribute__((address_space(3))) void*)(l), 16, 0, 0)

__device__ __forceinline__ u16 f2bf(float f) {
    unsigned u = __builtin_bit_cast(unsigned, f);
    u += 0x7fffu + ((u >> 16) & 1u);   // RNE
    return (u16)(u >> 16);
}

__device__ __forceinline__ float bf2f(u16 b) {
    unsigned u = ((unsigned)b) << 16;
    return __builtin_bit_cast(float, u);
}

// windowed token index -> image row index
__device__ __forceinline__ int win_to_img(int tok) {
    int win = tok >> 9, n = tok & 511;
    int wh = win >> 4, ww = (win >> 2) & 3, wd = win & 3;
    int ph = n >> 6, pw = (n >> 3) & 7, pd = n & 7;
    return ((wh * 8 + ph) * 32 + (ww * 8 + pw)) * 32 + (wd * 8 + pd);
}

// LayerNorm over C=512 (f32 input), one wave per token; windowed gather.
__global__ __launch_bounds__(256) void k_ln(const float* __restrict__ x,
                                            const float* __restrict__ w,
                                            const float* __restrict__ b,
                                            u16* __restrict__ out, int windowed) {
    int wave = threadIdx.x >> 6, lane = threadIdx.x & 63;
    int tok = blockIdx.x * 4 + wave;
    int src = windowed ? win_to_img(tok) : tok;
    const float* xr = x + (size_t)src * 512;
    float v[8];
#pragma unroll
    for (int i = 0; i < 2; i++) {
        float4 f = *(const float4*)(xr + i * 256 + lane * 4);
        v[i * 4 + 0] = f.x; v[i * 4 + 1] = f.y; v[i * 4 + 2] = f.z; v[i * 4 + 3] = f.w;
    }
    float s = 0.f;
#pragma unroll
    for (int i = 0; i < 8; i++) s += v[i];
#pragma unroll
    for (int m = 1; m < 64; m <<= 1) s += __shfl_xor(s, m);
    float mean = s * (1.0f / 512.0f);
    float vs = 0.f;
#pragma unroll
    for (int i = 0; i < 8; i++) { float d = v[i] - mean; vs += d * d; }
#pragma unroll
    for (int m = 1; m < 64; m <<= 1) vs += __shfl_xor(vs, m);
    float rstd = rsqrtf(vs * (1.0f / 512.0f) + LN_EPS);
    u16* orow = out + (size_t)tok * 512;
#pragma unroll
    for (int i = 0; i < 2; i++) {
        int c0 = i * 256 + lane * 4;
        ushort4 o;
        o.x = f2bf((v[i * 4 + 0] - mean) * rstd * w[c0 + 0] + b[c0 + 0]);
        o.y = f2bf((v[i * 4 + 1] - mean) * rstd * w[c0 + 1] + b[c0 + 1]);
        o.z = f2bf((v[i * 4 + 2] - mean) * rstd * w[c0 + 2] + b[c0 + 2]);
        o.w = f2bf((v[i * 4 + 3] - mean) * rstd * w[c0 + 3] + b[c0 + 3]);
        *(ushort4*)(orow + c0) = o;
    }
}

// LayerNorm over C=512 (bf16 input, straight rows) — LN2 on bf16 x1.
__global__ __launch_bounds__(256) void k_lnb(const u16* __restrict__ x,
                                             const float* __restrict__ w,
                                             const float* __restrict__ b,
                                             u16* __restrict__ out) {
    int wave = threadIdx.x >> 6, lane = threadIdx.x & 63;
    int tok = blockIdx.x * 4 + wave;
    const u16* xr = x + (size_t)tok * 512 + lane * 8;
    bfrag raw = *(const bfrag*)(xr);
    float v[8];
#pragma unroll
    for (int i = 0; i < 8; i++) v[i] = bf2f((u16)raw[i]);
    float s = 0.f;
#pragma unroll
    for (int i = 0; i < 8; i++) s += v[i];
#pragma unroll
    for (int m = 1; m < 64; m <<= 1) s += __shfl_xor(s, m);
    float mean = s * (1.0f / 512.0f);
    float vs = 0.f;
#pragma unroll
    for (int i = 0; i < 8; i++) { float d = v[i] - mean; vs += d * d; }
#pragma unroll
    for (int m = 1; m < 64; m <<= 1) vs += __shfl_xor(vs, m);
    float rstd = rsqrtf(vs * (1.0f / 512.0f) + LN_EPS);
    int c0 = lane * 8;
    ushort4 o0, o1;
    o0.x = f2bf((v[0] - mean) * rstd * w[c0 + 0] + b[c0 + 0]);
    o0.y = f2bf((v[1] - mean) * rstd * w[c0 + 1] + b[c0 + 1]);
    o0.z = f2bf((v[2] - mean) * rstd * w[c0 + 2] + b[c0 + 2]);
    o0.w = f2bf((v[3] - mean) * rstd * w[c0 + 3] + b[c0 + 3]);
    o1.x = f2bf((v[4] - mean) * rstd * w[c0 + 4] + b[c0 + 4]);
    o1.y = f2bf((v[5] - mean) * rstd * w[c0 + 5] + b[c0 + 5]);
    o1.z = f2bf((v[6] - mean) * rstd * w[c0 + 6] + b[c0 + 6]);
    o1.w = f2bf((v[7] - mean) * rstd * w[c0 + 7] + b[c0 + 7]);
    u16* orow = out + (size_t)tok * 512 + c0;
    *(ushort4*)(orow) = o0;
    *(ushort4*)(orow + 4) = o1;
}

// Merged prep: 4 weight transposes (f32 [K][N] -> bf16 [N][K]) + q scale/cast.
__global__ __launch_bounds__(256) void k_prep(const float* __restrict__ kv_w,
                                              const float* __restrict__ proj_w,
                                              const float* __restrict__ fc1_w,
                                              const float* __restrict__ fc2_w,
                                              const float* __restrict__ q,
                                              u16* __restrict__ kv_wt,
                                              u16* __restrict__ proj_wt,
                                              u16* __restrict__ fc1_wt,
                                              u16* __restrict__ fc2_wt,
                                              u16* __restrict__ qbf) {
    int i = blockIdx.x * 256 + threadIdx.x;
    if (i < 524288) {                       // kv_wt [1024][512]
        int n = i >> 9, k = i & 511;
        kv_wt[i] = f2bf(kv_w[k * 1024 + n]);
    } else if (i < 786432) {                // proj_wt [512][512]
        int j = i - 524288, n = j >> 9, k = j & 511;
        proj_wt[j] = f2bf(proj_w[k * 512 + n]);
    } else if (i < 1835008) {               // fc1_wt [2048][512]
        int j = i - 786432, n = j >> 9, k = j & 511;
        fc1_wt[j] = f2bf(fc1_w[k * 2048 + n]);
    } else if (i < 2883584) {               // fc2_wt [512][2048]
        int j = i - 1835008, n = j >> 11, k = j & 2047;
        fc2_wt[j] = f2bf(fc2_w[k * 512 + n]);
    } else {                                // qbf [8*512*64], pre-scaled
        int j = i - 2883584;
        qbf[j] = f2bf(q[j] * 0.125f);
    }
}

// ==== 128x128 GEMM, BK=32, 4 waves (2x2), 2-phase dbuf — kv/proj ====
// EPI 0: +bias -> K [win][h][key][d] / V^T [win][h][d][key]  (bf16)
// EPI 1: +bias, + resid(x)[image], scatter windowed->image -> bf16 x1
//        (LDS-restaged 128B coalesced stores; R4: scattered bf16 amplifies)
template <int EPI>
__global__ __launch_bounds__(256, 4) void k_gemm128(const u16* __restrict__ A,
                                                    const u16* __restrict__ Bt,
                                                    const float* __restrict__ bias,
                                                    void* __restrict__ Cout, int K, int Nn,
                                                    const float* __restrict__ resid,
                                                    void* __restrict__ Cout2) {
    __shared__ u16 As0[4096], Bs0[4096], As1[4096], Bs1[4096];
    int tid = threadIdx.x;
    int wave = tid >> 6, lane = tid & 63;
    int wr = wave >> 1, wc = wave & 1;

    int gx = Nn >> 7;
    int nwg = gridDim.x;
    int wg = blockIdx.x;
    int wgs = (wg & 7) * (nwg >> 3) + (wg >> 3);   // XCD chunking (nwg%8==0)
    int bn = wgs % gx, bm = wgs / gx;

    int rt = wave * 32 + (lane >> 2);
    int sxo = ((lane & 3) ^ ((rt ^ (rt >> 2)) & 3)) * 8;
    const u16* Ag = A + (size_t)(bm * 128 + rt) * K + sxo;
    const u16* Bg = Bt + (size_t)(bn * 128 + rt) * K + sxo;

    int fr = lane & 15, g = lane >> 4;
    int pco = (g ^ ((fr ^ (fr >> 2)) & 3)) * 8;

    ffrag acc[4][4] = {};

#define STAGE(AS, BS, k0)                                                      \
    {                                                                          \
        GLOAD16(Ag + (k0), AS + wave * 1024);                                  \
        GLOAD16(Ag + (k0) + 16 * K, AS + wave * 1024 + 512);                   \
        GLOAD16(Bg + (k0), BS + wave * 1024);                                  \
        GLOAD16(Bg + (k0) + 16 * K, BS + wave * 1024 + 512);                   \
    }
#define COMPUTE(AS, BS)                                                        \
    {                                                                          \
        bfrag a[4], b[4];                                                      \
        _Pragma("unroll") for (int m = 0; m < 4; m++)                          \
            a[m] = *(const bfrag*)(AS + (wr * 64 + m * 16 + fr) * 32 + pco);   \
        _Pragma("unroll") for (int n = 0; n < 4; n++)                          \
            b[n] = *(const bfrag*)(BS + (wc * 64 + n * 16 + fr) * 32 + pco);   \
        _Pragma("unroll") for (int m = 0; m < 4; m++)                          \
            _Pragma("unroll") for (int n = 0; n < 4; n++)                      \
                acc[m][n] = __builtin_amdgcn_mfma_f32_16x16x32_bf16(           \
                    a[m], b[n], acc[m][n], 0, 0, 0);                           \
    }

    int nt = K >> 5;
    STAGE(As0, Bs0, 0);
    __syncthreads();
    int t = 0;
    for (; t + 2 < nt; t += 2) {
        STAGE(As1, Bs1, (t + 1) * 32);
        COMPUTE(As0, Bs0);
        __syncthreads();
        STAGE(As0, Bs0, (t + 2) * 32);
        COMPUTE(As1, Bs1);
        __syncthreads();
    }
    STAGE(As1, Bs1, (nt - 1) * 32);
    COMPUTE(As0, Bs0);
    __syncthreads();
    COMPUTE(As1, Bs1);
#undef STAGE
#undef COMPUTE

    int gcolb = bn * 128 + wc * 64;
    int grb = bm * 128 + wr * 64;

    __syncthreads();   // safe to reuse staging LDS (all slots past last read)
    u16* ep = (wave == 0) ? As0 : (wave == 1) ? Bs0 : (wave == 2) ? As1 : Bs1;

    if constexpr (EPI == 0) {
        int h = (gcolb >> 6) & 7;
        bool isK = (gcolb < 512);
#pragma unroll
        for (int m = 0; m < 4; m++)
#pragma unroll
            for (int n = 0; n < 4; n++) {
                float bv = bias[gcolb + n * 16 + fr];
#pragma unroll
                for (int r = 0; r < 4; r++) {
                    int wq = m * 16 + g * 4 + r;
                    int wcc = n * 16 + fr;
                    float val = acc[m][n][r] + bv;
                    if (isK)
                        ep[wq * 64 + (wcc ^ ((wq & 7) << 3))] = f2bf(val);
                    else
                        ep[wcc * 64 + (wq ^ ((wcc & 7) << 3))] = f2bf(val);
                }
            }
#pragma unroll
        for (int rd = 0; rd < 8; rd++) {
            int row = rd * 8 + (lane >> 3);
            int ch = (lane & 7) ^ (row & 7);
            int4 v = *(const int4*)(ep + row * 64 + ch * 8);
            if (isK) {
                int tok = grb + row;
                int win = tok >> 9, key = tok & 511;
                *(int4*)(&((u16*)Cout)[(((size_t)(win * 8 + h)) * 512 + key) * 64 + (lane & 7) * 8]) = v;
            } else {
                int win = grb >> 9, key0 = grb & 511;
                *(int4*)(&((u16*)Cout2)[(((size_t)(win * 8 + h)) * 64 + row) * 512 + key0 + (lane & 7) * 8]) = v;
            }
        }
    } else {
        // EPI1: x1 = proj + bias + x (resid, image order), bf16, restaged
#pragma unroll
        for (int m = 0; m < 4; m++)
#pragma unroll
            for (int n = 0; n < 4; n++) {
                float bv = bias[gcolb + n * 16 + fr];
#pragma unroll
                for (int r = 0; r < 4; r++) {
                    int wq = m * 16 + g * 4 + r;
                    int ri = win_to_img(grb + wq);
                    float val = acc[m][n][r] + bv +
                                resid[(size_t)ri * 512 + gcolb + n * 16 + fr];
                    int wcc = n * 16 + fr;
                    ep[wq * 64 + (wcc ^ ((wq & 7) << 3))] = f2bf(val);
                }
            }
#pragma unroll
        for (int rd = 0; rd < 8; rd++) {
            int row = rd * 8 + (lane >> 3);
            int ch = (lane & 7) ^ (row & 7);
            int4 v = *(const int4*)(ep + row * 64 + ch * 8);
            int ri = win_to_img(grb + row);
            *(int4*)(&((u16*)Cout)[(size_t)ri * 512 + gcolb + (lane & 7) * 8]) = v;
        }
    }
}

// ==== 256x256 phased GEMM, BK=64, 8 waves (2Mx4N) — fc1/fc2 ====
// EPI 2: +bias, tanh-GELU -> bf16, LDS-restaged (fc1)
// EPI 3: +bias, + resid(x1 bf16) -> f32 direct (fc2)
template <int EPI>
__global__ __launch_bounds__(512, 2) void k_gemm256p(const u16* __restrict__ A,
                                                     const u16* __restrict__ Bt,
                                                     const float* __restrict__ bias,
                                                     void* __restrict__ Cout, int K, int Nn,
                                                     const void* __restrict__ resid) {
    __shared__ u16 sm[65536];   // 2 bufs x (A [256][64] @0 | B [256][64] @16384)
    int tid = threadIdx.x;
    int wave = tid >> 6, lane = tid & 63;
    int wm = wave >> 2, wn = wave & 3;

    int gx = Nn >> 8;
    int nwg = gridDim.x;
    int wg = blockIdx.x;
    int wgs = (wg & 7) * (nwg >> 3) + (wg >> 3);   // XCD chunking (nwg%8==0)
    int bn = wgs % gx, bm = wgs / gx;

    int sr = tid >> 3;
    int sf = (sr ^ (sr >> 2)) & 7;
    int sxo = ((tid & 7) ^ sf) * 8;
    const u16* Ag = A + (size_t)(bm * 256 + sr) * K + sxo;
    const u16* Bg = Bt + (size_t)(bn * 256 + sr) * K + sxo;
    size_t rowK = (size_t)64 * K;

    int fr = lane & 15, g = lane >> 4;
    int fb0 = (fr ^ (fr >> 2)) & 7;

    ffrag acc[8][4] = {};

#define STAGE256(SLOT, k0)                                                     \
    {                                                                          \
        u16* d = sm + (SLOT) * 32768 + wave * 512;                             \
        _Pragma("unroll") for (int i = 0; i < 4; i++)                          \
            GLOAD16(Ag + (k0) + i * rowK, d + i * 4096);                       \
        _Pragma("unroll") for (int i = 0; i < 4; i++)                          \
            GLOAD16(Bg + (k0) + i * rowK, d + 16384 + i * 4096);               \
    }

    int nt = K >> 6;
    STAGE256(0, 0);
    asm volatile("s_waitcnt vmcnt(0)" ::: "memory");
    __builtin_amdgcn_sched_barrier(0);
    __builtin_amdgcn_s_barrier();
    __builtin_amdgcn_sched_barrier(0);

#pragma unroll 1
    for (int t = 0; t < nt; ++t) {
        const u16* Ab = sm + (t & 1) * 32768;
        const u16* Bb = Ab + 16384;
        if (t + 1 < nt) STAGE256((t + 1) & 1, (size_t)(t + 1) * 64);
        bfrag bfr[8];
#pragma unroll
        for (int n = 0; n < 4; n++)
#pragma unroll
            for (int s = 0; s < 2; s++)
                bfr[n * 2 + s] = *(const bfrag*)(Bb + (wn * 64 + n * 16 + fr) * 64 +
                                  (((g + 4 * s) ^ fb0 ^ ((n & 1) << 2)) & 7) * 8);
#pragma unroll
        for (int q = 0; q < 4; q++) {
            bfrag afr[4];
#pragma unroll
            for (int mm = 0; mm < 2; mm++)
#pragma unroll
                for (int s = 0; s < 2; s++) {
                    int m = q * 2 + mm;
                    afr[mm * 2 + s] = *(const bfrag*)(Ab + (wm * 128 + m * 16 + fr) * 64 +
                                      (((g + 4 * s) ^ fb0 ^ ((m & 1) << 2)) & 7) * 8);
                }
            __builtin_amdgcn_s_setprio(1);
#pragma unroll
            for (int mm = 0; mm < 2; mm++)
#pragma unroll
                for (int n = 0; n < 4; n++)
#pragma unroll
                    for (int s = 0; s < 2; s++)
                        acc[q * 2 + mm][n] = __builtin_amdgcn_mfma_f32_16x16x32_bf16(
                            afr[mm * 2 + s], bfr[n * 2 + s], acc[q * 2 + mm][n], 0, 0, 0);
            __builtin_amdgcn_s_setprio(0);
        }
        asm volatile("s_waitcnt lgkmcnt(0)" ::: "memory");
        asm volatile("s_waitcnt vmcnt(0)" ::: "memory");
        __builtin_amdgcn_sched_barrier(0);
        __builtin_amdgcn_s_barrier();
        __builtin_amdgcn_sched_barrier(0);
    }
#undef STAGE256

    int gcb = bn * 256 + wn * 64;     // wave col base
    int grb = bm * 256 + wm * 128;    // wave row base

    if constexpr (EPI == 2) {
        u16* ep = sm + wave * 8192;
#pragma unroll
        for (int m = 0; m < 8; m++)
#pragma unroll
            for (int n = 0; n < 4; n++) {
                float bv = bias[gcb + n * 16 + fr];
#pragma unroll
                for (int r = 0; r < 4; r++) {
                    int rl = m * 16 + g * 4 + r;
                    int cl = n * 16 + fr;
                    float xx = acc[m][n][r] + bv;
                    float inner = fmaf(0.044715f * xx * xx, xx, xx);
                    float e = __expf(-1.5957691216f * inner);
                    float val = xx * __builtin_amdgcn_rcpf(1.0f + e);
                    ep[rl * 64 + (cl ^ ((rl & 7) << 3))] = f2bf(val);
                }
            }
#pragma unroll
        for (int it = 0; it < 16; it++) {
            int rl = it * 8 + (lane >> 3);
            int ch = (lane & 7) ^ (rl & 7);
            int4 v = *(const int4*)(ep + rl * 64 + ch * 8);
            *(int4*)(&((u16*)Cout)[(size_t)(grb + rl) * Nn + gcb + (lane & 7) * 8]) = v;
        }
    } else {
        const u16* rb = (const u16*)resid;   // bf16 x1
#pragma unroll
        for (int m = 0; m < 8; m++)
#pragma unroll
            for (int n = 0; n < 4; n++) {
                int col = gcb + n * 16 + fr;
                float bv = bias[col];
#pragma unroll
                for (int r = 0; r < 4; r++) {
                    int row = grb + m * 16 + g * 4 + r;
                    size_t o = (size_t)row * 512 + col;
                    ((float*)Cout)[o] = acc[m][n][r] + bv + bf2f(rb[o]);
                }
            }
    }
}

// Flash attention (R13-proven dataflow + deferred max/sum bookkeeping).
__global__ __launch_bounds__(256, 4) void k_attn(const u16* __restrict__ qb,
                                                 const u16* __restrict__ kb,
                                                 const u16* __restrict__ vtb,
                                                 u16* __restrict__ o) {
    __shared__ u16 K0[4096], K1[4096], V0[4096], V1[4096];  // [row 64][64]
    __shared__ u16 Ps[4096];                                 // [64][64] swizzled
    int bid = blockIdx.x;
    int wg = (bid & 7) * 512 + (bid >> 3);   // bijective XCD chunking (4096%8==0)
    int qc = wg & 7;
    int pair = wg >> 3;
    int hh = pair & 7, win = pair >> 3;
    int wave = threadIdx.x >> 6, lane = threadIdx.x & 63;
    const u16* kbw = kb + ((size_t)(win * 8 + hh)) * 512 * 64;
    const u16* vtw = vtb + ((size_t)(win * 8 + hh)) * 64 * 512;

    const u16* qrow = qb + ((size_t)hh * 512 + qc * 64 + (wave << 4) + (lane & 15)) * 64 + (lane >> 4) * 8;
    bfrag aq0 = *(const bfrag*)(qrow);
    bfrag aq1 = *(const bfrag*)(qrow + 32);

    ffrag acc[4] = {};
    float m_run[4], l_run[4];
#pragma unroll
    for (int r = 0; r < 4; r++) { m_run[r] = -1e30f; l_run[r] = 0.0f; }

    int srow = lane >> 3;
    int sxo = ((lane & 7) ^ srow) * 8;
    int fr = lane & 15;
    int fkc = lane >> 4;
    int kx0 = (fkc ^ (fr & 7)) * 8;
    int kx1 = ((fkc + 4) ^ (fr & 7)) * 8;
    int arow = (wave << 4) + fr;
    int pswz = (arow & 7) << 3;

#define STAGE_KV(KS, VS, kc)                                                   \
    {                                                                          \
        GLOAD16(kbw + (size_t)((kc) * 64 + wave * 8 + srow) * 64 + sxo,        \
                KS + wave * 512);                                              \
        GLOAD16(kbw + (size_t)((kc) * 64 + 32 + wave * 8 + srow) * 64 + sxo,   \
                KS + 2048 + wave * 512);                                       \
        GLOAD16(vtw + (size_t)(wave * 8 + srow) * 512 + (kc) * 64 + sxo,       \
                VS + wave * 512);                                              \
        GLOAD16(vtw + (size_t)(32 + wave * 8 + srow) * 512 + (kc) * 64 + sxo,  \
                VS + 2048 + wave * 512);                                       \
    }
#define ATT_COMPUTE(KS, VS)                                                    \
    {                                                                          \
        ffrag s[4] = {};                                                       \
        _Pragma("unroll") for (int j = 0; j < 4; j++) {                        \
            bfrag b0 = *(const bfrag*)(KS + (j * 16 + fr) * 64 + kx0);         \
            s[j] = __builtin_amdgcn_mfma_f32_16x16x32_bf16(aq0, b0, s[j], 0, 0, 0); \
            bfrag b1 = *(const bfrag*)(KS + (j * 16 + fr) * 64 + kx1);         \
            s[j] = __builtin_amdgcn_mfma_f32_16x16x32_bf16(aq1, b1, s[j], 0, 0, 0); \
        }                                                                      \
        int need = 0;                                                          \
        _Pragma("unroll") for (int r = 0; r < 4; r++) {                        \
            float mxj = fmaxf(fmaxf(s[0][r], s[1][r]),                         \
                              fmaxf(s[2][r], s[3][r]));                        \
            need |= (mxj > m_run[r] + 8.0f) ? 1 : 0;                           \
        }                                                                      \
        if (__any(need)) {                                                     \
            _Pragma("unroll") for (int r = 0; r < 4; r++) {                    \
                float mx = fmaxf(fmaxf(s[0][r], s[1][r]),                      \
                                 fmaxf(s[2][r], s[3][r]));                     \
                _Pragma("unroll") for (int d = 1; d < 16; d <<= 1)             \
                    mx = fmaxf(mx, __shfl_xor(mx, d));                         \
                float mnew = fmaxf(m_run[r], mx);                              \
                float alpha = __expf(m_run[r] - mnew);                         \
                m_run[r] = mnew;                                               \
                l_run[r] *= alpha;                                             \
                _Pragma("unroll") for (int j = 0; j < 4; j++)                  \
                    acc[j][r] *= alpha;                                        \
            }                                                                  \
        }                                                                      \
        _Pragma("unroll") for (int j = 0; j < 4; j++)                          \
            _Pragma("unroll") for (int r = 0; r < 4; r++) {                    \
                float p = __expf(s[j][r] - m_run[r]);                          \
                l_run[r] += p;                                                 \
                int prow = (wave << 4) + (lane >> 4) * 4 + r;                  \
                Ps[prow * 64 + ((j * 16 + fr) ^ ((prow & 7) << 3))] = f2bf(p); \
            }                                                                  \
        bfrag ap0 = *(const bfrag*)(&Ps[arow * 64 + ((fkc * 8) ^ pswz)]);      \
        bfrag ap1 = *(const bfrag*)(&Ps[arow * 64 + ((32 + fkc * 8) ^ pswz)]); \
        _Pragma("unroll") for (int j = 0; j < 4; j++) {                        \
            bfrag v0 = *(const bfrag*)(VS + (j * 16 + fr) * 64 + kx0);         \
            acc[j] = __builtin_amdgcn_mfma_f32_16x16x32_bf16(ap0, v0, acc[j], 0, 0, 0); \
            bfrag v1 = *(const bfrag*)(VS + (j * 16 + fr) * 64 + kx1);         \
            acc[j] = __builtin_amdgcn_mfma_f32_16x16x32_bf16(ap1, v1, acc[j], 0, 0, 0); \
        }                                                                      \
    }

    STAGE_KV(K0, V0, 0);
    __syncthreads();
#pragma unroll 1
    for (int kc = 0; kc < 8; kc += 2) {
        if (kc + 1 < 8) STAGE_KV(K1, V1, kc + 1);
        ATT_COMPUTE(K0, V0);
        __syncthreads();
        if (kc + 2 < 8) STAGE_KV(K0, V0, kc + 2);
        ATT_COMPUTE(K1, V1);
        __syncthreads();
    }
#undef STAGE_KV
#undef ATT_COMPUTE

#pragma unroll
    for (int r = 0; r < 4; r++) {
#pragma unroll
        for (int d = 1; d < 16; d <<= 1)
            l_run[r] += __shfl_xor(l_run[r], d);
    }

    int row0 = qc * 64 + (wave << 4) + (lane >> 4) * 4;
#pragma unroll
    for (int j = 0; j < 4; j++) {
        int col = hh * 64 + j * 16 + fr;
#pragma unroll
        for (int r = 0; r < 4; r++) {
            float val = acc[j][r] / l_run[r];
            o[((size_t)win * 512 + row0 + r) * 512 + col] = f2bf(val);
        }
    }
}

extern "C" void kernel_launch(void* const* d_in, const int* in_sizes, int n_in,
                              void* d_out, int out_size, void* d_ws, size_t ws_size,
                              hipStream_t stream) {
    const float* x      = (const float*)d_in[0];
    const float* q_ms   = (const float*)d_in[1];
    const float* n1w    = (const float*)d_in[2];
    const float* n1b    = (const float*)d_in[3];
    const float* kv_w   = (const float*)d_in[4];
    const float* kv_b   = (const float*)d_in[5];
    const float* proj_w = (const float*)d_in[6];
    const float* proj_b = (const float*)d_in[7];
    const float* n2w    = (const float*)d_in[8];
    const float* n2b    = (const float*)d_in[9];
    const float* fc1_w  = (const float*)d_in[10];
    const float* fc1_b  = (const float*)d_in[11];
    const float* fc2_w  = (const float*)d_in[12];
    const float* fc2_b  = (const float*)d_in[13];

    char* ws = (char*)d_ws;
    const size_t OFF_XNW = 0;           // bf16 [32768][512]   33,554,432 B
    const size_t OFF_KB  = 33554432;    // bf16 [64][8][512][64]  33,554,432 B
    const size_t OFF_VT  = 67108864;    // bf16 [64][8][64][512]  33,554,432 B
    const size_t OFF_O   = 100663296;   // bf16 [32768][512]   33,554,432 B
    const size_t OFF_HID = 0;           // bf16 [32768][2048] (aliases dead bufs)
    const size_t OFF_X1  = 134217728;   // bf16 [32768][512]   33,554,432 B
    const size_t OFF_XN2 = 201326592;   // bf16 [32768][512]   33,554,432 B
    const size_t OFF_W   = 234881024;   // transposed weights + q
    u16* xnw = (u16*)(ws + OFF_XNW);
    u16* kbb = (u16*)(ws + OFF_KB);
    u16* vtb = (u16*)(ws + OFF_VT);
    u16* ob  = (u16*)(ws + OFF_O);
    u16* hid = (u16*)(ws + OFF_HID);
    u16* x1b = (u16*)(ws + OFF_X1);
    u16* xn2 = (u16*)(ws + OFF_XN2);
    u16* kv_wt   = (u16*)(ws + OFF_W);        // [1024][512]
    u16* proj_wt = kv_wt + 512 * 1024;        // [512][512]
    u16* fc1_wt  = proj_wt + 512 * 512;       // [2048][512]
    u16* fc2_wt  = fc1_wt + 512 * 2048;       // [512][2048]
    u16* qbf     = fc2_wt + 2048 * 512;       // [8][512][64]
    size_t need = OFF_W + (size_t)(512 * 1024 + 512 * 512 + 512 * 2048 + 2048 * 512 + 8 * 512 * 64) * 2;
    if (ws_size < need) return;

    k_ln<<<8192, 256, 0, stream>>>(x, n1w, n1b, xnw, 1);
    k_prep<<<12288, 256, 0, stream>>>(kv_w, proj_w, fc1_w, fc2_w, q_ms,
                                      kv_wt, proj_wt, fc1_wt, fc2_wt, qbf);

    k_gemm128<0><<<2048, 256, 0, stream>>>(xnw, kv_wt, kv_b, kbb, 512, 1024, nullptr, vtb);
    k_attn<<<dim3(4096), 256, 0, stream>>>(qbf, kbb, vtb, ob);
    k_gemm128<1><<<1024, 256, 0, stream>>>(ob, proj_wt, proj_b, x1b, 512, 512, x, nullptr);
    k_lnb<<<8192, 256, 0, stream>>>(x1b, n2w, n2b, xn2);
    k_gemm256p<2><<<1024, 512, 0, stream>>>(xn2, fc1_wt, fc1_b, hid, 512, 2048, nullptr);
    k_gemm256p<3><<<256, 512, 0, stream>>>(hid, fc2_wt, fc2_b, d_out, 2048, 512, x1b);
}